// Round 8
// baseline (182.017 us; speedup 1.0000x reference)
//
#include <hip/hip_runtime.h>

typedef __bf16 bf16;
typedef bf16 bf16x8 __attribute__((ext_vector_type(8)));
typedef bf16 bf16x4 __attribute__((ext_vector_type(4)));
typedef float f32x4 __attribute__((ext_vector_type(4)));

#define MFMA16(a, b, c) __builtin_amdgcn_mfma_f32_16x16x32_bf16(a, b, c, 0, 0, 0)

// async global->LDS, 16B per lane; lds dest is wave-uniform base (+lane*16 by HW)
__device__ __forceinline__ void gload_lds16(const bf16* g, bf16* l) {
  __builtin_amdgcn_global_load_lds(
      (const __attribute__((address_space(1))) void*)g,
      (__attribute__((address_space(3))) void*)l, 16, 0, 0);
}

// ---------------- merged prep kernel ----------------
// blocks [0,4096):      x fp32 -> bf16 (8 el/thread, 16B loads+stores)
// blocks [4096,4608):   zero convp (2 MB) — re-zeroed every launch (ws poisoned)
// blocks [4608,5632):   W transposes (Wq swizzled | Wkv | Wo plain)
// blocks [5632,6656):   sr_w [o][i][p] -> srwT [o][p*256+i]
__global__ void k_prep(const float* __restrict__ x, const float* __restrict__ Wq,
                       const float* __restrict__ Wkv, const float* __restrict__ Wo,
                       const float* __restrict__ srw,
                       bf16* __restrict__ x_bf, bf16* __restrict__ WqT,
                       bf16* __restrict__ WkvT, bf16* __restrict__ WoT,
                       bf16* __restrict__ srwT, float* __restrict__ convp) {
  int bid = blockIdx.x, tid = threadIdx.x;
  if (bid < 4096) {
    int i = (bid * 256 + tid) * 8;
    float4 v0 = *(const float4*)(x + i);
    float4 v1 = *(const float4*)(x + i + 4);
    bf16x8 o;
    o[0] = (bf16)v0.x; o[1] = (bf16)v0.y; o[2] = (bf16)v0.z; o[3] = (bf16)v0.w;
    o[4] = (bf16)v1.x; o[5] = (bf16)v1.y; o[6] = (bf16)v1.z; o[7] = (bf16)v1.w;
    *(bf16x8*)(x_bf + i) = o;
  } else if (bid < 4608) {
    int idx = (bid - 4096) * 256 + tid;  // 131072 float4 = 2 MB
    ((float4*)convp)[idx] = (float4){0.f, 0.f, 0.f, 0.f};
  } else if (bid < 5632) {
    int id = (bid - 4608) * 256 + tid;  // 0..262143
    if (id < 65536) {                   // WqT (swizzled)
      int c = id >> 8, r = id & 255;    // c = out, r = in
      WqT[c * 256 + (r ^ ((c & 7) << 3))] = (bf16)Wq[r * 256 + c];
    } else if (id < 196608) {           // WkvT
      int l = id - 65536;
      int c = l >> 8, r = l & 255;      // c in 0..511
      WkvT[l] = (bf16)Wkv[r * 512 + c];
    } else {                            // WoT (plain transpose [out][in])
      int l = id - 196608;
      int c = l >> 8, r = l & 255;
      WoT[l] = (bf16)Wo[r * 256 + c];
    }
  } else {
    int id4 = ((bid - 5632) * 256 + tid) * 4;  // input-linear o*4096+i*16+p
    int o = id4 >> 12, rem = id4 & 4095;
    int i = rem >> 4, p = rem & 15;            // p in {0,4,8,12}
    float4 v = *(const float4*)(srw + id4);
    srwT[(o << 12) + ((p + 0) << 8) + i] = (bf16)v.x;
    srwT[(o << 12) + ((p + 1) << 8) + i] = (bf16)v.y;
    srwT[(o << 12) + ((p + 2) << 8) + i] = (bf16)v.z;
    srwT[(o << 12) + ((p + 3) << 8) + i] = (bf16)v.w;
  }
}

// ---------------- 64x64-tile MFMA GEMM (KV projection) ----------------
// EMODE 2: KV scatter (XOR-swizzled cols for attn's global_load_lds staging):
//          K  -> [bh][key][d ^ ((key&7)<<3)]
//          V^T-> [bh][d][key ^ ((d&7)<<3)]
template <int AMODE, int EMODE>
__global__ __launch_bounds__(256, 2) void k_gemm(
    const bf16* __restrict__ A, const bf16* __restrict__ Bt,
    void* __restrict__ Cout, const float* __restrict__ bias,
    int M, int N, int K) {
  constexpr int LDT = 72;  // 64 + 8 pad
  __shared__ alignas(16) bf16 As[64 * LDT];
  __shared__ alignas(16) bf16 Bs[64 * LDT];
  int tid = threadIdx.x;
  int m0 = blockIdx.x * 64, n0 = blockIdx.y * 64;
  int kbeg = blockIdx.z * K;
  int wave = tid >> 6, lane = tid & 63;
  int quad = lane >> 4, l16 = lane & 15;

  f32x4 acc[4];
#pragma unroll
  for (int i = 0; i < 4; i++) acc[i] = (f32x4){0.f, 0.f, 0.f, 0.f};

  for (int k0 = kbeg; k0 < kbeg + K; k0 += 64) {
#pragma unroll
    for (int t = 0; t < 2; t++) {
      int c = tid + t * 256;
      int row = c >> 3, c8 = (c & 7) * 8;
      *(bf16x8*)&As[row * LDT + c8] =
          *(const bf16x8*)(A + (size_t)(m0 + row) * K + k0 + c8);
      *(bf16x8*)&Bs[row * LDT + c8] =
          *(const bf16x8*)(Bt + (size_t)(n0 + row) * K + k0 + c8);
    }
    __syncthreads();
#pragma unroll
    for (int kk = 0; kk < 64; kk += 32) {
      bf16x8 af = *(const bf16x8*)&As[(wave * 16 + l16) * LDT + kk + quad * 8];
#pragma unroll
      for (int nt = 0; nt < 4; nt++) {
        bf16x8 bfr = *(const bf16x8*)&Bs[(nt * 16 + l16) * LDT + kk + quad * 8];
        acc[nt] = MFMA16(af, bfr, acc[nt]);
      }
    }
    __syncthreads();
  }

  int rbase = m0 + wave * 16 + quad * 4;
#pragma unroll
  for (int nt = 0; nt < 4; nt++) {
    int col = n0 + nt * 16 + l16;
#pragma unroll
    for (int r = 0; r < 4; r++) {
      float v = acc[nt][r];
      int row = rbase + r;
      if constexpr (EMODE == 2) {
        int b = row >> 8, key = row & 255;
        int isv = col >> 8, c2 = col & 255;
        int hh = c2 >> 6, d = c2 & 63;
        int bh = b * 4 + hh;
        bf16* dst = (bf16*)Cout;
        if (isv == 0)
          dst[(((size_t)bh) * 256 + key) * 64 + (d ^ ((key & 7) << 3))] = (bf16)v;
        else
          dst[32 * 256 * 64 + (((size_t)bh) * 64 + d) * 256 + (key ^ ((d & 7) << 3))] = (bf16)v;
      } else {
        ((float*)Cout)[(size_t)row * N + col] = v + bias[col];
      }
    }
  }
}

// ---------------- 128x128-tile MFMA GEMM (m97 structure; conv im2col) ----------------
// EMODE 4: split-K via fp32 atomicAdd into convp [2048][256] (zeroed in k_prep)
template <int AMODE, int EMODE>
__global__ __launch_bounds__(256, 2) void k_gemm128(
    const bf16* __restrict__ A, const bf16* __restrict__ Bt,
    void* __restrict__ Cout, const float* __restrict__ bias,
    int M, int N, int K) {
  __shared__ alignas(16) bf16 As[128 * 64];
  __shared__ alignas(16) bf16 Bs[128 * 64];
  int tid = threadIdx.x;
  int m0 = blockIdx.x * 128, n0 = blockIdx.y * 128;
  int kbeg = blockIdx.z * K;
  int wave = tid >> 6, lane = tid & 63;
  int quad = lane >> 4, l16 = lane & 15;
  int wr = wave >> 1, wc = wave & 1;

  f32x4 acc[4][4];
#pragma unroll
  for (int i = 0; i < 4; i++)
#pragma unroll
    for (int j = 0; j < 4; j++) acc[i][j] = (f32x4){0.f, 0.f, 0.f, 0.f};

  for (int k0 = kbeg; k0 < kbeg + K; k0 += 64) {
#pragma unroll
    for (int t = 0; t < 4; t++) {
      int chunk = wave * 4 + t;            // 0..15, wave-uniform
      int row = chunk * 8 + (lane >> 3);   // 8 rows per chunk
      int c8 = (lane & 7) * 8;             // bf16 offset within row (16B/lane)
      const bf16* asrc;
      if constexpr (AMODE == 0) {
        asrc = A + (size_t)(m0 + row) * K + k0 + c8;
      } else {
        int m = m0 + row;
        int b = m >> 8, tt = m & 255;
        int oh = tt >> 4, ow = tt & 15;
        int p = k0 >> 8;            // patch position (BK=64 never straddles p)
        int kh = p >> 2, kw = p & 3;
        int tok = (oh * 4 + kh) * 64 + ow * 4 + kw;
        asrc = A + ((size_t)(b * 4096 + tok) << 8) + (k0 & 255) + c8;
      }
      gload_lds16(asrc, As + chunk * 512);
      gload_lds16(Bt + (size_t)(n0 + row) * ((AMODE == 1) ? 4096 : K) + k0 + c8,
                  Bs + chunk * 512);
    }
    __syncthreads();
#pragma unroll
    for (int kk = 0; kk < 64; kk += 32) {
      bf16x8 af[4], bfr[4];
#pragma unroll
      for (int mt = 0; mt < 4; mt++)
        af[mt] = *(const bf16x8*)&As[(wr * 64 + mt * 16 + l16) * 64 + kk + quad * 8];
#pragma unroll
      for (int nt = 0; nt < 4; nt++)
        bfr[nt] = *(const bf16x8*)&Bs[(wc * 64 + nt * 16 + l16) * 64 + kk + quad * 8];
#pragma unroll
      for (int mt = 0; mt < 4; mt++)
#pragma unroll
        for (int nt = 0; nt < 4; nt++)
          acc[mt][nt] = MFMA16(af[mt], bfr[nt], acc[mt][nt]);
    }
    __syncthreads();
  }

#pragma unroll
  for (int mt = 0; mt < 4; mt++) {
    int rbase = m0 + wr * 64 + mt * 16 + quad * 4;
#pragma unroll
    for (int nt = 0; nt < 4; nt++) {
      int col = n0 + wc * 64 + nt * 16 + l16;
#pragma unroll
      for (int r = 0; r < 4; r++) {
        float v = acc[mt][nt][r];
        int row = rbase + r;
        if constexpr (EMODE == 3) {
          ((float*)Cout)[(size_t)row * N + col] = v + bias[col];
        } else {  // EMODE 4: atomic split-K accumulate
          atomicAdd(&((float*)Cout)[(size_t)row * N + col], v);
        }
      }
    }
  }
}

// ---------------- final GEMM: BM=64, BN=256 (single n-tile -> A read once) ----------------
// out[32768][256] fp32 = AO[32768][256] @ WoT[256][256]^T + bo. Grid 512 blocks.
__global__ __launch_bounds__(256, 3) void k_gemm_out(
    const bf16* __restrict__ A, const bf16* __restrict__ Bt,
    float* __restrict__ out, const float* __restrict__ bias) {
  __shared__ alignas(16) bf16 As[64 * 64];    //  8 KB
  __shared__ alignas(16) bf16 Bs[256 * 64];   // 32 KB
  int tid = threadIdx.x;
  int m0 = blockIdx.x * 64;
  int wave = tid >> 6, lane = tid & 63;
  int quad = lane >> 4, l16 = lane & 15;

  f32x4 acc[4][4];
#pragma unroll
  for (int i = 0; i < 4; i++)
#pragma unroll
    for (int j = 0; j < 4; j++) acc[i][j] = (f32x4){0.f, 0.f, 0.f, 0.f};

  for (int k0 = 0; k0 < 256; k0 += 64) {
    int c8 = (lane & 7) * 8;
#pragma unroll
    for (int t = 0; t < 2; t++) {  // A: 8 chunks of 8 rows
      int chunk = wave * 2 + t;
      int row = chunk * 8 + (lane >> 3);
      gload_lds16(A + (size_t)(m0 + row) * 256 + k0 + c8, As + chunk * 512);
    }
#pragma unroll
    for (int t = 0; t < 8; t++) {  // B: 32 chunks (all 256 out-cols)
      int chunk = wave * 8 + t;
      int row = chunk * 8 + (lane >> 3);
      gload_lds16(Bt + (size_t)row * 256 + k0 + c8, Bs + chunk * 512);
    }
    __syncthreads();
#pragma unroll
    for (int kk = 0; kk < 64; kk += 32) {
      bf16x8 af[4], bfr[4];
#pragma unroll
      for (int mt = 0; mt < 4; mt++)
        af[mt] = *(const bf16x8*)&As[(mt * 16 + l16) * 64 + kk + quad * 8];
#pragma unroll
      for (int nt = 0; nt < 4; nt++)
        bfr[nt] = *(const bf16x8*)&Bs[(wave * 64 + nt * 16 + l16) * 64 + kk + quad * 8];
#pragma unroll
      for (int mt = 0; mt < 4; mt++)
#pragma unroll
        for (int nt = 0; nt < 4; nt++)
          acc[mt][nt] = MFMA16(af[mt], bfr[nt], acc[mt][nt]);
    }
    __syncthreads();
  }

#pragma unroll
  for (int mt = 0; mt < 4; mt++) {
    int rbase = m0 + mt * 16 + quad * 4;
#pragma unroll
    for (int nt = 0; nt < 4; nt++) {
      int col = wave * 64 + nt * 16 + l16;
      float bb = bias[col];
#pragma unroll
      for (int r = 0; r < 4; r++)
        out[(size_t)(rbase + r) * 256 + col] = acc[mt][nt][r] + bb;
    }
  }
}

// ---------------- LayerNorm (convp + sr_b -> bf16) ----------------
__global__ void k_ln(const float* __restrict__ part, const float* __restrict__ srb,
                     const float* __restrict__ g, const float* __restrict__ bb,
                     bf16* __restrict__ out) {
  int row = blockIdx.x * 4 + (threadIdx.x >> 6);
  int lane = threadIdx.x & 63;
  size_t off = (size_t)row * 256 + lane * 4;
  float4 v = *(const float4*)&part[off];
  int c = lane * 4;
  v.x += srb[c + 0]; v.y += srb[c + 1]; v.z += srb[c + 2]; v.w += srb[c + 3];
  float s = v.x + v.y + v.z + v.w;
#pragma unroll
  for (int i = 1; i < 64; i <<= 1) s += __shfl_xor(s, i, 64);
  float mu = s * (1.f / 256.f);
  float d0 = v.x - mu, d1 = v.y - mu, d2 = v.z - mu, d3 = v.w - mu;
  float q = d0 * d0 + d1 * d1 + d2 * d2 + d3 * d3;
#pragma unroll
  for (int i = 1; i < 64; i <<= 1) q += __shfl_xor(q, i, 64);
  float rs = rsqrtf(q * (1.f / 256.f) + 1e-5f);
  bf16x4 o;
  o[0] = (bf16)(d0 * rs * g[c + 0] + bb[c + 0]);
  o[1] = (bf16)(d1 * rs * g[c + 1] + bb[c + 1]);
  o[2] = (bf16)(d2 * rs * g[c + 2] + bb[c + 2]);
  o[3] = (bf16)(d3 * rs * g[c + 3] + bb[c + 3]);
  *(bf16x4*)&out[(size_t)row * 256 + c] = o;
}

// ---------------- attention with fused Q-projection (R7 winner, unchanged) ----
// grid (32 bh, 64 qtiles), block 256 (4 waves), LDS 48 KiB -> 3 blocks/CU.
__global__ __launch_bounds__(256, 3) void k_attn(
    const bf16* __restrict__ xbf,  // [B*4096][256]
    const bf16* __restrict__ WqT,  // [256 out][256 in ^ ((out&7)<<3)]
    const bf16* __restrict__ Kg,   // [32][256][64]  cols ^ ((key&7)<<3)
    const bf16* __restrict__ Vg,   // [32][64][256]  cols ^ ((d&7)<<3)
    bf16* __restrict__ O) {        // [B*4096][256]
  int bh = blockIdx.x, qt = blockIdx.y;
  int b = bh >> 2, h = bh & 3;
  int tid = threadIdx.x, wave = tid >> 6, lane = tid & 63;
  int quad = lane >> 4, l16 = lane & 15;

  __shared__ alignas(16) bf16 smem[24576];  // 49152 B
  bf16* R0  = smem;          // [64][256] Wq -> [256][64] K -> [64][256] P
  bf16* R2a = smem + 16384;  // [64][64] V quarter (even)
  bf16* R2b = smem + 20480;  // [64][64] Qs -> V quarter (odd)

  const bf16* Kbh = Kg + ((size_t)bh << 14);
  const bf16* Vbh = Vg + ((size_t)bh << 14);
  const bf16* Wqh = WqT + ((size_t)(h * 64) << 8);

  // ---- stage Wq head (32KB) + V quarter 0 (8KB); x A-frags -> regs ----
#pragma unroll
  for (int t = 0; t < 8; t++) {
    int chunk = t * 4 + wave;
    gload_lds16(Wqh + chunk * 512 + lane * 8, R0 + chunk * 512);
  }
#pragma unroll
  for (int t = 0; t < 2; t++) {
    int chunk = wave * 2 + t;  // wave w covers rows [w*16, w*16+16)
    gload_lds16(Vbh + (chunk * 8 + (lane >> 3)) * 256 + 0 + (lane & 7) * 8,
                R2a + chunk * 512);
  }
  const bf16* xrow =
      xbf + (((size_t)(b * 4096 + qt * 64 + wave * 16 + l16)) << 8) + quad * 8;
  bf16x8 ax[8];
#pragma unroll
  for (int j = 0; j < 8; j++) ax[j] = *(const bf16x8*)(xrow + j * 32);

  __syncthreads();  // B1: Wq + Vq0 resident (ax drained too)

  // ---- Q = x @ Wq_head^T ----
  f32x4 q[4];
#pragma unroll
  for (int i = 0; i < 4; i++) q[i] = (f32x4){0.f, 0.f, 0.f, 0.f};
  __builtin_amdgcn_s_setprio(1);
#pragma unroll
  for (int j = 0; j < 8; j++) {
#pragma unroll
    for (int nt = 0; nt < 4; nt++) {
      int wrow = nt * 16 + l16;
      bf16x8 bw = *(const bf16x8*)&R0[wrow * 256 +
                                      ((j * 32 + quad * 8) ^ ((wrow & 7) << 3))];
      q[nt] = MFMA16(ax[j], bw, q[nt]);
    }
  }
  __builtin_amdgcn_s_setprio(0);
  __syncthreads();  // B2: Wq reads done -> R0 free (V drain harmless)

  // ---- Qs (swizzled, wave-private rows) -> R2b; stage K -> R0 ----
#pragma unroll
  for (int nt = 0; nt < 4; nt++)
#pragma unroll
    for (int r = 0; r < 4; r++) {
      int qr = wave * 16 + quad * 4 + r;
      R2b[qr * 64 + ((nt * 16 + l16) ^ ((qr & 7) << 3))] = (bf16)q[nt][r];
    }
#pragma unroll
  for (int t = 0; t < 8; t++) {
    int chunk = t * 4 + wave;
    gload_lds16(Kbh + chunk * 512 + lane * 8, R0 + chunk * 512);
  }
  __syncthreads();  // B3: K resident (Qs rows are wave-private anyway)

  int arow = wave * 16 + l16;
  int asw = (arow & 7) << 3;
  bf16x8 aq0 = *(const bf16x8*)&R2b[arow * 64 + ((quad * 8) ^ asw)];
  bf16x8 aq1 = *(const bf16x8*)&R2b[arow * 64 + ((32 + quad * 8) ^ asw)];
  // wave-local: ensure our ds_reads completed before DMA may overwrite R2b.
  // (wave w's Vq1 chunks land exactly on wave w's own Qs rows.)
  asm volatile("s_waitcnt lgkmcnt(0)" ::: "memory");
#pragma unroll
  for (int t = 0; t < 2; t++) {
    int chunk = wave * 2 + t;  // wave w overwrites only its own Qs rows
    gload_lds16(Vbh + (chunk * 8 + (lane >> 3)) * 256 + 64 + (lane & 7) * 8,
                R2b + chunk * 512);
  }

  // ---- S = Q K^T ----
  f32x4 s[16];
#pragma unroll
  for (int i = 0; i < 16; i++) s[i] = (f32x4){0.f, 0.f, 0.f, 0.f};
  __builtin_amdgcn_s_setprio(1);
#pragma unroll
  for (int nt = 0; nt < 16; nt++) {
    int krow = nt * 16 + l16;
    const bf16* kb = R0 + krow * 64;
    int sw = (krow & 7) << 3;
    bf16x8 b0 = *(const bf16x8*)(kb + ((quad * 8) ^ sw));
    bf16x8 b1 = *(const bf16x8*)(kb + ((32 + quad * 8) ^ sw));
    s[nt] = MFMA16(aq0, b0, s[nt]);
    s[nt] = MFMA16(aq1, b1, s[nt]);
  }
  __builtin_amdgcn_s_setprio(0);

  // softmax over 256 keys
  const float scale = 0.125f;
#pragma unroll
  for (int r = 0; r < 4; r++) {
    float m = -1e30f;
#pragma unroll
    for (int nt = 0; nt < 16; nt++) m = fmaxf(m, s[nt][r]);
#pragma unroll
    for (int i = 1; i < 16; i <<= 1) m = fmaxf(m, __shfl_xor(m, i, 64));
    float sum = 0.f;
#pragma unroll
    for (int nt = 0; nt < 16; nt++) {
      float e = __expf((s[nt][r] - m) * scale);
      s[nt][r] = e;
      sum += e;
    }
#pragma unroll
    for (int i = 1; i < 16; i <<= 1) sum += __shfl_xor(sum, i, 64);
    float inv = 1.f / sum;
#pragma unroll
    for (int nt = 0; nt < 16; nt++) s[nt][r] *= inv;
  }

  __syncthreads();  // B4: K reads done -> R0 free for P; Vq1 resident in R2b

  // ---- P -> R0 swizzled [64][256] (wave-private rows; no barrier after) ----
#pragma unroll
  for (int nt = 0; nt < 16; nt++)
#pragma unroll
    for (int r = 0; r < 4; r++) {
      int prow = wave * 16 + quad * 4 + r;
      R0[prow * 256 + ((nt * 16 + l16) ^ ((prow & 7) << 3))] = (bf16)s[nt][r];
    }

  const bf16* pb = R0 + arow * 256;
  f32x4 o[4];
#pragma unroll
  for (int i = 0; i < 4; i++) o[i] = (f32x4){0.f, 0.f, 0.f, 0.f};

  // ---- O = P V over 4 key-quarters, V double-buffered R2a/R2b ----
#pragma unroll
  for (int cq = 0; cq < 4; cq++) {
    const bf16* Vbuf = (cq & 1) ? R2b : R2a;
    __builtin_amdgcn_s_setprio(1);
#pragma unroll
    for (int k0 = 0; k0 < 64; k0 += 32) {
      bf16x8 ap = *(const bf16x8*)(pb + ((cq * 64 + k0 + quad * 8) ^ asw));
#pragma unroll
      for (int nt = 0; nt < 4; nt++) {
        int vrow = nt * 16 + l16;
        bf16x8 bv = *(const bf16x8*)&Vbuf[vrow * 64 +
                                          ((k0 + quad * 8) ^ ((vrow & 7) << 3))];
        o[nt] = MFMA16(ap, bv, o[nt]);
      }
    }
    __builtin_amdgcn_s_setprio(0);
    if (cq < 3) {
      __syncthreads();  // quarter cq reads done everywhere; quarter cq+1 resident
      if (cq < 2) {     // stage quarter cq+2 into the buffer just freed
        bf16* nb = (cq & 1) ? R2b : R2a;
#pragma unroll
        for (int t = 0; t < 2; t++) {
          int chunk = wave * 2 + t;
          gload_lds16(Vbh + (chunk * 8 + (lane >> 3)) * 256 + (cq + 2) * 64 +
                          (lane & 7) * 8,
                      nb + chunk * 512);
        }
      }
    }
  }

  size_t orow = (size_t)b * 4096 + qt * 64 + wave * 16 + quad * 4;
#pragma unroll
  for (int nt = 0; nt < 4; nt++) {
    int col = h * 64 + nt * 16 + l16;
#pragma unroll
    for (int r = 0; r < 4; r++) O[(orow + r) * 256 + col] = (bf16)o[nt][r];
  }
}

// ---------------- launch ----------------
extern "C" void kernel_launch(void* const* d_in, const int* in_sizes, int n_in,
                              void* d_out, int out_size, void* d_ws, size_t ws_size,
                              hipStream_t stream) {
  (void)in_sizes; (void)n_in; (void)out_size; (void)ws_size;
  const float* x   = (const float*)d_in[0];
  const float* Wq  = (const float*)d_in[3];
  const float* Wkv = (const float*)d_in[4];
  const float* srw = (const float*)d_in[5];
  const float* srb = (const float*)d_in[6];
  const float* lng = (const float*)d_in[7];
  const float* lnb = (const float*)d_in[8];
  const float* Wo  = (const float*)d_in[9];
  const float* bo  = (const float*)d_in[10];
  float* out = (float*)d_out;

  char* ws = (char*)d_ws;
  bf16*  x_bf  = (bf16*)(ws + 0);          // 16,777,216 B
  bf16*  AObuf = (bf16*)(ws + 16777216);   // 16,777,216
  float* convp = (float*)(ws + 33554432);  //  2,097,152 (atomic accumulator)
  bf16*  WqT   = (bf16*)(ws + 50331648);   //    131,072
  bf16*  WkvT  = (bf16*)(ws + 50462720);   //    262,144
  bf16*  WoT   = (bf16*)(ws + 50724864);   //    131,072
  bf16*  srwT  = (bf16*)(ws + 50855936);   //  2,097,152
  bf16*  xln   = (bf16*)(ws + 52953088);   //  1,048,576
  bf16*  kvbuf = (bf16*)(ws + 54001664);   //  2,097,152 (K then V^T, swizzled)

  k_prep<<<6656, 256, 0, stream>>>(x, Wq, Wkv, Wo, srw, x_bf, WqT, WkvT, WoT, srwT, convp);
  // conv (im2col GEMM), split-K 8x512 -> fp32 atomic accumulate into convp [2048][256]
  k_gemm128<1, 4><<<dim3(16, 2, 8), 256, 0, stream>>>(x_bf, srwT, convp, nullptr, 2048, 256, 512);
  // LayerNorm (+sr_b) -> bf16 [2048][256]
  k_ln<<<512, 256, 0, stream>>>(convp, srb, lng, lnb, xln);
  // KV = xln @ Wkv -> K, V^T (swizzled) bf16
  k_gemm<0, 2><<<dim3(32, 8), 256, 0, stream>>>(xln, WkvT, kvbuf, nullptr, 2048, 512, 256);
  // attention (Q-projection fused)
  k_attn<<<dim3(32, 64), 256, 0, stream>>>(x_bf, WqT, kvbuf, kvbuf + (size_t)32 * 256 * 64, AObuf);
  // out = AO @ Wo + bo -> fp32 d_out (BM=64, BN=256: AO read once)
  k_gemm_out<<<512, 256, 0, stream>>>(AObuf, WoT, out, bo);
}

// Round 9
// 176.104 us; speedup vs baseline: 1.0336x; 1.0336x over previous
//
#include <hip/hip_runtime.h>

typedef __bf16 bf16;
typedef bf16 bf16x8 __attribute__((ext_vector_type(8)));
typedef bf16 bf16x4 __attribute__((ext_vector_type(4)));
typedef float f32x4 __attribute__((ext_vector_type(4)));

#define MFMA16(a, b, c) __builtin_amdgcn_mfma_f32_16x16x32_bf16(a, b, c, 0, 0, 0)

// async global->LDS, 16B per lane; lds dest is wave-uniform base (+lane*16 by HW)
__device__ __forceinline__ void gload_lds16(const bf16* g, bf16* l) {
  __builtin_amdgcn_global_load_lds(
      (const __attribute__((address_space(1))) void*)g,
      (__attribute__((address_space(3))) void*)l, 16, 0, 0);
}

// ---------------- merged prep kernel ----------------
// blocks [0,4096):      x fp32 -> bf16 (8 el/thread, 16B loads+stores)
// blocks [4096,5120):   W transposes (Wq swizzled | Wkv | Wo plain)
// blocks [5120,6144):   sr_w [o][i][p] -> srwT [o][p*256+i]
__global__ void k_prep(const float* __restrict__ x, const float* __restrict__ Wq,
                       const float* __restrict__ Wkv, const float* __restrict__ Wo,
                       const float* __restrict__ srw,
                       bf16* __restrict__ x_bf, bf16* __restrict__ WqT,
                       bf16* __restrict__ WkvT, bf16* __restrict__ WoT,
                       bf16* __restrict__ srwT) {
  int bid = blockIdx.x, tid = threadIdx.x;
  if (bid < 4096) {
    int i = (bid * 256 + tid) * 8;
    float4 v0 = *(const float4*)(x + i);
    float4 v1 = *(const float4*)(x + i + 4);
    bf16x8 o;
    o[0] = (bf16)v0.x; o[1] = (bf16)v0.y; o[2] = (bf16)v0.z; o[3] = (bf16)v0.w;
    o[4] = (bf16)v1.x; o[5] = (bf16)v1.y; o[6] = (bf16)v1.z; o[7] = (bf16)v1.w;
    *(bf16x8*)(x_bf + i) = o;
  } else if (bid < 5120) {
    int id = (bid - 4096) * 256 + tid;  // 0..262143
    if (id < 65536) {                   // WqT (swizzled)
      int c = id >> 8, r = id & 255;    // c = out, r = in
      WqT[c * 256 + (r ^ ((c & 7) << 3))] = (bf16)Wq[r * 256 + c];
    } else if (id < 196608) {           // WkvT
      int l = id - 65536;
      int c = l >> 8, r = l & 255;      // c in 0..511
      WkvT[l] = (bf16)Wkv[r * 512 + c];
    } else {                            // WoT (plain transpose [out][in])
      int l = id - 196608;
      int c = l >> 8, r = l & 255;
      WoT[l] = (bf16)Wo[r * 256 + c];
    }
  } else {
    int id4 = ((bid - 5120) * 256 + tid) * 4;  // input-linear o*4096+i*16+p
    int o = id4 >> 12, rem = id4 & 4095;
    int i = rem >> 4, p = rem & 15;            // p in {0,4,8,12}
    float4 v = *(const float4*)(srw + id4);
    srwT[(o << 12) + ((p + 0) << 8) + i] = (bf16)v.x;
    srwT[(o << 12) + ((p + 1) << 8) + i] = (bf16)v.y;
    srwT[(o << 12) + ((p + 2) << 8) + i] = (bf16)v.z;
    srwT[(o << 12) + ((p + 3) << 8) + i] = (bf16)v.w;
  }
}

// ---------------- 64x64-tile MFMA GEMM (KV projection) ----------------
// EMODE 2: KV scatter (XOR-swizzled cols for attn's global_load_lds staging):
//          K  -> [bh][key][d ^ ((key&7)<<3)]
//          V^T-> [bh][d][key ^ ((d&7)<<3)]
template <int AMODE, int EMODE>
__global__ __launch_bounds__(256, 2) void k_gemm(
    const bf16* __restrict__ A, const bf16* __restrict__ Bt,
    void* __restrict__ Cout, const float* __restrict__ bias,
    int M, int N, int K) {
  constexpr int LDT = 72;  // 64 + 8 pad
  __shared__ alignas(16) bf16 As[64 * LDT];
  __shared__ alignas(16) bf16 Bs[64 * LDT];
  int tid = threadIdx.x;
  int m0 = blockIdx.x * 64, n0 = blockIdx.y * 64;
  int kbeg = blockIdx.z * K;
  int wave = tid >> 6, lane = tid & 63;
  int quad = lane >> 4, l16 = lane & 15;

  f32x4 acc[4];
#pragma unroll
  for (int i = 0; i < 4; i++) acc[i] = (f32x4){0.f, 0.f, 0.f, 0.f};

  for (int k0 = kbeg; k0 < kbeg + K; k0 += 64) {
#pragma unroll
    for (int t = 0; t < 2; t++) {
      int c = tid + t * 256;
      int row = c >> 3, c8 = (c & 7) * 8;
      *(bf16x8*)&As[row * LDT + c8] =
          *(const bf16x8*)(A + (size_t)(m0 + row) * K + k0 + c8);
      *(bf16x8*)&Bs[row * LDT + c8] =
          *(const bf16x8*)(Bt + (size_t)(n0 + row) * K + k0 + c8);
    }
    __syncthreads();
#pragma unroll
    for (int kk = 0; kk < 64; kk += 32) {
      bf16x8 af = *(const bf16x8*)&As[(wave * 16 + l16) * LDT + kk + quad * 8];
#pragma unroll
      for (int nt = 0; nt < 4; nt++) {
        bf16x8 bfr = *(const bf16x8*)&Bs[(nt * 16 + l16) * LDT + kk + quad * 8];
        acc[nt] = MFMA16(af, bfr, acc[nt]);
      }
    }
    __syncthreads();
  }

  int rbase = m0 + wave * 16 + quad * 4;
#pragma unroll
  for (int nt = 0; nt < 4; nt++) {
    int col = n0 + nt * 16 + l16;
#pragma unroll
    for (int r = 0; r < 4; r++) {
      float v = acc[nt][r];
      int row = rbase + r;
      if constexpr (EMODE == 2) {
        int b = row >> 8, key = row & 255;
        int isv = col >> 8, c2 = col & 255;
        int hh = c2 >> 6, d = c2 & 63;
        int bh = b * 4 + hh;
        bf16* dst = (bf16*)Cout;
        if (isv == 0)
          dst[(((size_t)bh) * 256 + key) * 64 + (d ^ ((key & 7) << 3))] = (bf16)v;
        else
          dst[32 * 256 * 64 + (((size_t)bh) * 64 + d) * 256 + (key ^ ((d & 7) << 3))] = (bf16)v;
      } else {
        ((float*)Cout)[(size_t)row * N + col] = v + bias[col];
      }
    }
  }
}

// ---------------- 128x128-tile MFMA GEMM (m97 structure; conv im2col) ----------------
template <int AMODE, int EMODE>
__global__ __launch_bounds__(256, 2) void k_gemm128(
    const bf16* __restrict__ A, const bf16* __restrict__ Bt,
    void* __restrict__ Cout, const float* __restrict__ bias,
    int M, int N, int K) {
  __shared__ alignas(16) bf16 As[128 * 64];
  __shared__ alignas(16) bf16 Bs[128 * 64];
  int tid = threadIdx.x;
  int m0 = blockIdx.x * 128, n0 = blockIdx.y * 128;
  int kbeg = blockIdx.z * K;
  int wave = tid >> 6, lane = tid & 63;
  int quad = lane >> 4, l16 = lane & 15;
  int wr = wave >> 1, wc = wave & 1;

  f32x4 acc[4][4];
#pragma unroll
  for (int i = 0; i < 4; i++)
#pragma unroll
    for (int j = 0; j < 4; j++) acc[i][j] = (f32x4){0.f, 0.f, 0.f, 0.f};

  for (int k0 = kbeg; k0 < kbeg + K; k0 += 64) {
#pragma unroll
    for (int t = 0; t < 4; t++) {
      int chunk = wave * 4 + t;            // 0..15, wave-uniform
      int row = chunk * 8 + (lane >> 3);   // 8 rows per chunk
      int c8 = (lane & 7) * 8;             // bf16 offset within row (16B/lane)
      const bf16* asrc;
      if constexpr (AMODE == 0) {
        asrc = A + (size_t)(m0 + row) * K + k0 + c8;
      } else {
        int m = m0 + row;
        int b = m >> 8, tt = m & 255;
        int oh = tt >> 4, ow = tt & 15;
        int p = k0 >> 8;            // patch position (BK=64 never straddles p)
        int kh = p >> 2, kw = p & 3;
        int tok = (oh * 4 + kh) * 64 + ow * 4 + kw;
        asrc = A + ((size_t)(b * 4096 + tok) << 8) + (k0 & 255) + c8;
      }
      gload_lds16(asrc, As + chunk * 512);
      gload_lds16(Bt + (size_t)(n0 + row) * ((AMODE == 1) ? 4096 : K) + k0 + c8,
                  Bs + chunk * 512);
    }
    __syncthreads();
#pragma unroll
    for (int kk = 0; kk < 64; kk += 32) {
      bf16x8 af[4], bfr[4];
#pragma unroll
      for (int mt = 0; mt < 4; mt++)
        af[mt] = *(const bf16x8*)&As[(wr * 64 + mt * 16 + l16) * 64 + kk + quad * 8];
#pragma unroll
      for (int nt = 0; nt < 4; nt++)
        bfr[nt] = *(const bf16x8*)&Bs[(wc * 64 + nt * 16 + l16) * 64 + kk + quad * 8];
#pragma unroll
      for (int mt = 0; mt < 4; mt++)
#pragma unroll
        for (int nt = 0; nt < 4; nt++)
          acc[mt][nt] = MFMA16(af[mt], bfr[nt], acc[mt][nt]);
    }
    __syncthreads();
  }

#pragma unroll
  for (int mt = 0; mt < 4; mt++) {
    int rbase = m0 + wr * 64 + mt * 16 + quad * 4;
#pragma unroll
    for (int nt = 0; nt < 4; nt++) {
      int col = n0 + wc * 64 + nt * 16 + l16;
#pragma unroll
      for (int r = 0; r < 4; r++) {
        float v = acc[mt][nt][r];
        int row = rbase + r;
        if constexpr (EMODE == 3) {
          ((float*)Cout)[(size_t)row * N + col] = v + bias[col];
        } else {  // EMODE 4
          ((float*)Cout)[((size_t)blockIdx.z * M + row) * N + col] = v;
        }
      }
    }
  }
}

// ---------------- final GEMM: BM=64, BN=256 (single n-tile -> A read once) ----------------
// out[32768][256] fp32 = AO[32768][256] @ WoT[256][256]^T + bo. Grid 512 blocks.
__global__ __launch_bounds__(256, 3) void k_gemm_out(
    const bf16* __restrict__ A, const bf16* __restrict__ Bt,
    float* __restrict__ out, const float* __restrict__ bias) {
  __shared__ alignas(16) bf16 As[64 * 64];    //  8 KB
  __shared__ alignas(16) bf16 Bs[256 * 64];   // 32 KB
  int tid = threadIdx.x;
  int m0 = blockIdx.x * 64;
  int wave = tid >> 6, lane = tid & 63;
  int quad = lane >> 4, l16 = lane & 15;

  f32x4 acc[4][4];
#pragma unroll
  for (int i = 0; i < 4; i++)
#pragma unroll
    for (int j = 0; j < 4; j++) acc[i][j] = (f32x4){0.f, 0.f, 0.f, 0.f};

  for (int k0 = 0; k0 < 256; k0 += 64) {
    int c8 = (lane & 7) * 8;
#pragma unroll
    for (int t = 0; t < 2; t++) {  // A: 8 chunks of 8 rows
      int chunk = wave * 2 + t;
      int row = chunk * 8 + (lane >> 3);
      gload_lds16(A + (size_t)(m0 + row) * 256 + k0 + c8, As + chunk * 512);
    }
#pragma unroll
    for (int t = 0; t < 8; t++) {  // B: 32 chunks (all 256 out-cols)
      int chunk = wave * 8 + t;
      int row = chunk * 8 + (lane >> 3);
      gload_lds16(Bt + (size_t)row * 256 + k0 + c8, Bs + chunk * 512);
    }
    __syncthreads();
#pragma unroll
    for (int kk = 0; kk < 64; kk += 32) {
      bf16x8 af[4], bfr[4];
#pragma unroll
      for (int mt = 0; mt < 4; mt++)
        af[mt] = *(const bf16x8*)&As[(mt * 16 + l16) * 64 + kk + quad * 8];
#pragma unroll
      for (int nt = 0; nt < 4; nt++)
        bfr[nt] = *(const bf16x8*)&Bs[(wave * 64 + nt * 16 + l16) * 64 + kk + quad * 8];
#pragma unroll
      for (int mt = 0; mt < 4; mt++)
#pragma unroll
        for (int nt = 0; nt < 4; nt++)
          acc[mt][nt] = MFMA16(af[mt], bfr[nt], acc[mt][nt]);
    }
    __syncthreads();
  }

#pragma unroll
  for (int mt = 0; mt < 4; mt++) {
    int rbase = m0 + mt * 16 + quad * 4;
#pragma unroll
    for (int nt = 0; nt < 4; nt++) {
      int col = wave * 64 + nt * 16 + l16;
      float bb = bias[col];
#pragma unroll
      for (int r = 0; r < 4; r++)
        out[(size_t)(rbase + r) * 256 + col] = acc[mt][nt][r] + bb;
    }
  }
}

// ---------------- LayerNorm (sum of 8 fp32 partials + sr_b -> bf16) ----------------
__global__ void k_ln(const float* __restrict__ part, const float* __restrict__ srb,
                     const float* __restrict__ g, const float* __restrict__ bb,
                     bf16* __restrict__ out) {
  int row = blockIdx.x * 4 + (threadIdx.x >> 6);
  int lane = threadIdx.x & 63;
  size_t off = (size_t)row * 256 + lane * 4;
  float4 v = *(const float4*)&part[off];
#pragma unroll
  for (int z = 1; z < 8; z++) {
    float4 p = *(const float4*)&part[(size_t)z * 2048 * 256 + off];
    v.x += p.x; v.y += p.y; v.z += p.z; v.w += p.w;
  }
  int c = lane * 4;
  v.x += srb[c + 0]; v.y += srb[c + 1]; v.z += srb[c + 2]; v.w += srb[c + 3];
  float s = v.x + v.y + v.z + v.w;
#pragma unroll
  for (int i = 1; i < 64; i <<= 1) s += __shfl_xor(s, i, 64);
  float mu = s * (1.f / 256.f);
  float d0 = v.x - mu, d1 = v.y - mu, d2 = v.z - mu, d3 = v.w - mu;
  float q = d0 * d0 + d1 * d1 + d2 * d2 + d3 * d3;
#pragma unroll
  for (int i = 1; i < 64; i <<= 1) q += __shfl_xor(q, i, 64);
  float rs = rsqrtf(q * (1.f / 256.f) + 1e-5f);
  bf16x4 o;
  o[0] = (bf16)(d0 * rs * g[c + 0] + bb[c + 0]);
  o[1] = (bf16)(d1 * rs * g[c + 1] + bb[c + 1]);
  o[2] = (bf16)(d2 * rs * g[c + 2] + bb[c + 2]);
  o[3] = (bf16)(d3 * rs * g[c + 3] + bb[c + 3]);
  *(bf16x4*)&out[(size_t)row * 256 + c] = o;
}

// ---------------- attention with fused Q-projection (R7 winner, unchanged) ----
// grid (32 bh, 64 qtiles), block 256 (4 waves), LDS 48 KiB -> 3 blocks/CU.
__global__ __launch_bounds__(256, 3) void k_attn(
    const bf16* __restrict__ xbf,  // [B*4096][256]
    const bf16* __restrict__ WqT,  // [256 out][256 in ^ ((out&7)<<3)]
    const bf16* __restrict__ Kg,   // [32][256][64]  cols ^ ((key&7)<<3)
    const bf16* __restrict__ Vg,   // [32][64][256]  cols ^ ((d&7)<<3)
    bf16* __restrict__ O) {        // [B*4096][256]
  int bh = blockIdx.x, qt = blockIdx.y;
  int b = bh >> 2, h = bh & 3;
  int tid = threadIdx.x, wave = tid >> 6, lane = tid & 63;
  int quad = lane >> 4, l16 = lane & 15;

  __shared__ alignas(16) bf16 smem[24576];  // 49152 B
  bf16* R0  = smem;          // [64][256] Wq -> [256][64] K -> [64][256] P
  bf16* R2a = smem + 16384;  // [64][64] V quarter (even)
  bf16* R2b = smem + 20480;  // [64][64] Qs -> V quarter (odd)

  const bf16* Kbh = Kg + ((size_t)bh << 14);
  const bf16* Vbh = Vg + ((size_t)bh << 14);
  const bf16* Wqh = WqT + ((size_t)(h * 64) << 8);

  // ---- stage Wq head (32KB) + V quarter 0 (8KB); x A-frags -> regs ----
#pragma unroll
  for (int t = 0; t < 8; t++) {
    int chunk = t * 4 + wave;
    gload_lds16(Wqh + chunk * 512 + lane * 8, R0 + chunk * 512);
  }
#pragma unroll
  for (int t = 0; t < 2; t++) {
    int chunk = wave * 2 + t;  // wave w covers rows [w*16, w*16+16)
    gload_lds16(Vbh + (chunk * 8 + (lane >> 3)) * 256 + 0 + (lane & 7) * 8,
                R2a + chunk * 512);
  }
  const bf16* xrow =
      xbf + (((size_t)(b * 4096 + qt * 64 + wave * 16 + l16)) << 8) + quad * 8;
  bf16x8 ax[8];
#pragma unroll
  for (int j = 0; j < 8; j++) ax[j] = *(const bf16x8*)(xrow + j * 32);

  __syncthreads();  // B1: Wq + Vq0 resident (ax drained too)

  // ---- Q = x @ Wq_head^T ----
  f32x4 q[4];
#pragma unroll
  for (int i = 0; i < 4; i++) q[i] = (f32x4){0.f, 0.f, 0.f, 0.f};
  __builtin_amdgcn_s_setprio(1);
#pragma unroll
  for (int j = 0; j < 8; j++) {
#pragma unroll
    for (int nt = 0; nt < 4; nt++) {
      int wrow = nt * 16 + l16;
      bf16x8 bw = *(const bf16x8*)&R0[wrow * 256 +
                                      ((j * 32 + quad * 8) ^ ((wrow & 7) << 3))];
      q[nt] = MFMA16(ax[j], bw, q[nt]);
    }
  }
  __builtin_amdgcn_s_setprio(0);
  __syncthreads();  // B2: Wq reads done -> R0 free (V drain harmless)

  // ---- Qs (swizzled, wave-private rows) -> R2b; stage K -> R0 ----
#pragma unroll
  for (int nt = 0; nt < 4; nt++)
#pragma unroll
    for (int r = 0; r < 4; r++) {
      int qr = wave * 16 + quad * 4 + r;
      R2b[qr * 64 + ((nt * 16 + l16) ^ ((qr & 7) << 3))] = (bf16)q[nt][r];
    }
#pragma unroll
  for (int t = 0; t < 8; t++) {
    int chunk = t * 4 + wave;
    gload_lds16(Kbh + chunk * 512 + lane * 8, R0 + chunk * 512);
  }
  __syncthreads();  // B3: K resident (Qs rows are wave-private anyway)

  int arow = wave * 16 + l16;
  int asw = (arow & 7) << 3;
  bf16x8 aq0 = *(const bf16x8*)&R2b[arow * 64 + ((quad * 8) ^ asw)];
  bf16x8 aq1 = *(const bf16x8*)&R2b[arow * 64 + ((32 + quad * 8) ^ asw)];
  // wave-local: ensure our ds_reads completed before DMA may overwrite R2b.
  // (wave w's Vq1 chunks land exactly on wave w's own Qs rows.)
  asm volatile("s_waitcnt lgkmcnt(0)" ::: "memory");
#pragma unroll
  for (int t = 0; t < 2; t++) {
    int chunk = wave * 2 + t;  // wave w overwrites only its own Qs rows
    gload_lds16(Vbh + (chunk * 8 + (lane >> 3)) * 256 + 64 + (lane & 7) * 8,
                R2b + chunk * 512);
  }

  // ---- S = Q K^T ----
  f32x4 s[16];
#pragma unroll
  for (int i = 0; i < 16; i++) s[i] = (f32x4){0.f, 0.f, 0.f, 0.f};
  __builtin_amdgcn_s_setprio(1);
#pragma unroll
  for (int nt = 0; nt < 16; nt++) {
    int krow = nt * 16 + l16;
    const bf16* kb = R0 + krow * 64;
    int sw = (krow & 7) << 3;
    bf16x8 b0 = *(const bf16x8*)(kb + ((quad * 8) ^ sw));
    bf16x8 b1 = *(const bf16x8*)(kb + ((32 + quad * 8) ^ sw));
    s[nt] = MFMA16(aq0, b0, s[nt]);
    s[nt] = MFMA16(aq1, b1, s[nt]);
  }
  __builtin_amdgcn_s_setprio(0);

  // softmax over 256 keys
  const float scale = 0.125f;
#pragma unroll
  for (int r = 0; r < 4; r++) {
    float m = -1e30f;
#pragma unroll
    for (int nt = 0; nt < 16; nt++) m = fmaxf(m, s[nt][r]);
#pragma unroll
    for (int i = 1; i < 16; i <<= 1) m = fmaxf(m, __shfl_xor(m, i, 64));
    float sum = 0.f;
#pragma unroll
    for (int nt = 0; nt < 16; nt++) {
      float e = __expf((s[nt][r] - m) * scale);
      s[nt][r] = e;
      sum += e;
    }
#pragma unroll
    for (int i = 1; i < 16; i <<= 1) sum += __shfl_xor(sum, i, 64);
    float inv = 1.f / sum;
#pragma unroll
    for (int nt = 0; nt < 16; nt++) s[nt][r] *= inv;
  }

  __syncthreads();  // B4: K reads done -> R0 free for P; Vq1 resident in R2b

  // ---- P -> R0 swizzled [64][256] (wave-private rows; no barrier after) ----
#pragma unroll
  for (int nt = 0; nt < 16; nt++)
#pragma unroll
    for (int r = 0; r < 4; r++) {
      int prow = wave * 16 + quad * 4 + r;
      R0[prow * 256 + ((nt * 16 + l16) ^ ((prow & 7) << 3))] = (bf16)s[nt][r];
    }

  const bf16* pb = R0 + arow * 256;
  f32x4 o[4];
#pragma unroll
  for (int i = 0; i < 4; i++) o[i] = (f32x4){0.f, 0.f, 0.f, 0.f};

  // ---- O = P V over 4 key-quarters, V double-buffered R2a/R2b ----
#pragma unroll
  for (int cq = 0; cq < 4; cq++) {
    const bf16* Vbuf = (cq & 1) ? R2b : R2a;
    __builtin_amdgcn_s_setprio(1);
#pragma unroll
    for (int k0 = 0; k0 < 64; k0 += 32) {
      bf16x8 ap = *(const bf16x8*)(pb + ((cq * 64 + k0 + quad * 8) ^ asw));
#pragma unroll
      for (int nt = 0; nt < 4; nt++) {
        int vrow = nt * 16 + l16;
        bf16x8 bv = *(const bf16x8*)&Vbuf[vrow * 64 +
                                          ((k0 + quad * 8) ^ ((vrow & 7) << 3))];
        o[nt] = MFMA16(ap, bv, o[nt]);
      }
    }
    __builtin_amdgcn_s_setprio(0);
    if (cq < 3) {
      __syncthreads();  // quarter cq reads done everywhere; quarter cq+1 resident
      if (cq < 2) {     // stage quarter cq+2 into the buffer just freed
        bf16* nb = (cq & 1) ? R2b : R2a;
#pragma unroll
        for (int t = 0; t < 2; t++) {
          int chunk = wave * 2 + t;
          gload_lds16(Vbh + (chunk * 8 + (lane >> 3)) * 256 + (cq + 2) * 64 +
                          (lane & 7) * 8,
                      nb + chunk * 512);
        }
      }
    }
  }

  size_t orow = (size_t)b * 4096 + qt * 64 + wave * 16 + quad * 4;
#pragma unroll
  for (int nt = 0; nt < 4; nt++) {
    int col = h * 64 + nt * 16 + l16;
#pragma unroll
    for (int r = 0; r < 4; r++) O[(orow + r) * 256 + col] = (bf16)o[nt][r];
  }
}

// ---------------- launch ----------------
extern "C" void kernel_launch(void* const* d_in, const int* in_sizes, int n_in,
                              void* d_out, int out_size, void* d_ws, size_t ws_size,
                              hipStream_t stream) {
  (void)in_sizes; (void)n_in; (void)out_size; (void)ws_size;
  const float* x   = (const float*)d_in[0];
  const float* Wq  = (const float*)d_in[3];
  const float* Wkv = (const float*)d_in[4];
  const float* srw = (const float*)d_in[5];
  const float* srb = (const float*)d_in[6];
  const float* lng = (const float*)d_in[7];
  const float* lnb = (const float*)d_in[8];
  const float* Wo  = (const float*)d_in[9];
  const float* bo  = (const float*)d_in[10];
  float* out = (float*)d_out;

  char* ws = (char*)d_ws;
  bf16*  x_bf  = (bf16*)(ws + 0);          // 16,777,216 B
  bf16*  AObuf = (bf16*)(ws + 16777216);   // 16,777,216
  float* convp = (float*)(ws + 33554432);  // 16,777,216 (8 partials)
  bf16*  WqT   = (bf16*)(ws + 50331648);   //    131,072
  bf16*  WkvT  = (bf16*)(ws + 50462720);   //    262,144
  bf16*  WoT   = (bf16*)(ws + 50724864);   //    131,072
  bf16*  srwT  = (bf16*)(ws + 50855936);   //  2,097,152
  bf16*  xln   = (bf16*)(ws + 52953088);   //  1,048,576
  bf16*  kvbuf = (bf16*)(ws + 54001664);   //  2,097,152 (K then V^T, swizzled)

  k_prep<<<6144, 256, 0, stream>>>(x, Wq, Wkv, Wo, srw, x_bf, WqT, WkvT, WoT, srwT);
  // conv (im2col GEMM), split-K 8x512 -> fp32 partials [8][2048][256]
  k_gemm128<1, 4><<<dim3(16, 2, 8), 256, 0, stream>>>(x_bf, srwT, convp, nullptr, 2048, 256, 512);
  // LayerNorm (+partial reduce +sr_b) -> bf16 [2048][256]
  k_ln<<<512, 256, 0, stream>>>(convp, srb, lng, lnb, xln);
  // KV = xln @ Wkv -> K, V^T (swizzled) bf16
  k_gemm<0, 2><<<dim3(32, 8), 256, 0, stream>>>(xln, WkvT, kvbuf, nullptr, 2048, 512, 256);
  // attention (Q-projection fused)
  k_attn<<<dim3(32, 64), 256, 0, stream>>>(x_bf, WqT, kvbuf, kvbuf + (size_t)32 * 256 * 64, AObuf);
  // out = AO @ Wo + bo -> fp32 d_out (BM=64, BN=256: AO read once)
  k_gemm_out<<<512, 256, 0, stream>>>(AObuf, WoT, out, bo);
}

// Round 12
// 172.663 us; speedup vs baseline: 1.0542x; 1.0199x over previous
//
#include <hip/hip_runtime.h>

typedef __bf16 bf16;
typedef bf16 bf16x8 __attribute__((ext_vector_type(8)));
typedef bf16 bf16x4 __attribute__((ext_vector_type(4)));
typedef float f32x4 __attribute__((ext_vector_type(4)));

#define MFMA16(a, b, c) __builtin_amdgcn_mfma_f32_16x16x32_bf16(a, b, c, 0, 0, 0)

// async global->LDS, 16B per lane; lds dest is wave-uniform base (+lane*16 by HW)
__device__ __forceinline__ void gload_lds16(const bf16* g, bf16* l) {
  __builtin_amdgcn_global_load_lds(
      (const __attribute__((address_space(1))) void*)g,
      (__attribute__((address_space(3))) void*)l, 16, 0, 0);
}

// ---------------- merged prep kernel ----------------
// blocks [0,4096):      x fp32 -> bf16 (8 el/thread, 16B loads+stores)
// blocks [4096,5120):   W transposes (Wq swizzled | Wkv | Wo plain)
// blocks [5120,6144):   sr_w [o][i][p] -> srwT [o][p*256+i]
__global__ void k_prep(const float* __restrict__ x, const float* __restrict__ Wq,
                       const float* __restrict__ Wkv, const float* __restrict__ Wo,
                       const float* __restrict__ srw,
                       bf16* __restrict__ x_bf, bf16* __restrict__ WqT,
                       bf16* __restrict__ WkvT, bf16* __restrict__ WoT,
                       bf16* __restrict__ srwT) {
  int bid = blockIdx.x, tid = threadIdx.x;
  if (bid < 4096) {
    int i = (bid * 256 + tid) * 8;
    float4 v0 = *(const float4*)(x + i);
    float4 v1 = *(const float4*)(x + i + 4);
    bf16x8 o;
    o[0] = (bf16)v0.x; o[1] = (bf16)v0.y; o[2] = (bf16)v0.z; o[3] = (bf16)v0.w;
    o[4] = (bf16)v1.x; o[5] = (bf16)v1.y; o[6] = (bf16)v1.z; o[7] = (bf16)v1.w;
    *(bf16x8*)(x_bf + i) = o;
  } else if (bid < 5120) {
    int id = (bid - 4096) * 256 + tid;  // 0..262143
    if (id < 65536) {                   // WqT (swizzled)
      int c = id >> 8, r = id & 255;    // c = out, r = in
      WqT[c * 256 + (r ^ ((c & 7) << 3))] = (bf16)Wq[r * 256 + c];
    } else if (id < 196608) {           // WkvT
      int l = id - 65536;
      int c = l >> 8, r = l & 255;      // c in 0..511
      WkvT[l] = (bf16)Wkv[r * 512 + c];
    } else {                            // WoT (plain transpose [out][in])
      int l = id - 196608;
      int c = l >> 8, r = l & 255;
      WoT[l] = (bf16)Wo[r * 256 + c];
    }
  } else {
    int id4 = ((bid - 5120) * 256 + tid) * 4;  // input-linear o*4096+i*16+p
    int o = id4 >> 12, rem = id4 & 4095;
    int i = rem >> 4, p = rem & 15;            // p in {0,4,8,12}
    float4 v = *(const float4*)(srw + id4);
    srwT[(o << 12) + ((p + 0) << 8) + i] = (bf16)v.x;
    srwT[(o << 12) + ((p + 1) << 8) + i] = (bf16)v.y;
    srwT[(o << 12) + ((p + 2) << 8) + i] = (bf16)v.z;
    srwT[(o << 12) + ((p + 3) << 8) + i] = (bf16)v.w;
  }
}

// ---------------- 64x64-tile MFMA GEMM (KV projection) ----------------
// EMODE 2: KV scatter (XOR-swizzled cols for attn's global_load_lds staging):
//          K  -> [bh][key][d ^ ((key&7)<<3)]         (64-wide rows, 8-group XOR)
//          V^T-> [bh][d][key ^ ((d&3)<<3)]           (32-wide eighths: bits 3-4 only)
template <int AMODE, int EMODE>
__global__ __launch_bounds__(256, 2) void k_gemm(
    const bf16* __restrict__ A, const bf16* __restrict__ Bt,
    void* __restrict__ Cout, const float* __restrict__ bias,
    int M, int N, int K) {
  constexpr int LDT = 72;  // 64 + 8 pad
  __shared__ alignas(16) bf16 As[64 * LDT];
  __shared__ alignas(16) bf16 Bs[64 * LDT];
  int tid = threadIdx.x;
  int m0 = blockIdx.x * 64, n0 = blockIdx.y * 64;
  int kbeg = blockIdx.z * K;
  int wave = tid >> 6, lane = tid & 63;
  int quad = lane >> 4, l16 = lane & 15;

  f32x4 acc[4];
#pragma unroll
  for (int i = 0; i < 4; i++) acc[i] = (f32x4){0.f, 0.f, 0.f, 0.f};

  for (int k0 = kbeg; k0 < kbeg + K; k0 += 64) {
#pragma unroll
    for (int t = 0; t < 2; t++) {
      int c = tid + t * 256;
      int row = c >> 3, c8 = (c & 7) * 8;
      *(bf16x8*)&As[row * LDT + c8] =
          *(const bf16x8*)(A + (size_t)(m0 + row) * K + k0 + c8);
      *(bf16x8*)&Bs[row * LDT + c8] =
          *(const bf16x8*)(Bt + (size_t)(n0 + row) * K + k0 + c8);
    }
    __syncthreads();
#pragma unroll
    for (int kk = 0; kk < 64; kk += 32) {
      bf16x8 af = *(const bf16x8*)&As[(wave * 16 + l16) * LDT + kk + quad * 8];
#pragma unroll
      for (int nt = 0; nt < 4; nt++) {
        bf16x8 bfr = *(const bf16x8*)&Bs[(nt * 16 + l16) * LDT + kk + quad * 8];
        acc[nt] = MFMA16(af, bfr, acc[nt]);
      }
    }
    __syncthreads();
  }

  int rbase = m0 + wave * 16 + quad * 4;
#pragma unroll
  for (int nt = 0; nt < 4; nt++) {
    int col = n0 + nt * 16 + l16;
#pragma unroll
    for (int r = 0; r < 4; r++) {
      float v = acc[nt][r];
      int row = rbase + r;
      if constexpr (EMODE == 2) {
        int b = row >> 8, key = row & 255;
        int isv = col >> 8, c2 = col & 255;
        int hh = c2 >> 6, d = c2 & 63;
        int bh = b * 4 + hh;
        bf16* dst = (bf16*)Cout;
        if (isv == 0)
          dst[(((size_t)bh) * 256 + key) * 64 + (d ^ ((key & 7) << 3))] = (bf16)v;
        else
          dst[32 * 256 * 64 + (((size_t)bh) * 64 + d) * 256 + (key ^ ((d & 3) << 3))] = (bf16)v;
      } else {
        ((float*)Cout)[(size_t)row * N + col] = v + bias[col];
      }
    }
  }
}

// ---------------- 128x128-tile MFMA GEMM (m97 structure; conv im2col) ----------------
template <int AMODE, int EMODE>
__global__ __launch_bounds__(256, 2) void k_gemm128(
    const bf16* __restrict__ A, const bf16* __restrict__ Bt,
    void* __restrict__ Cout, const float* __restrict__ bias,
    int M, int N, int K) {
  __shared__ alignas(16) bf16 As[128 * 64];
  __shared__ alignas(16) bf16 Bs[128 * 64];
  int tid = threadIdx.x;
  int m0 = blockIdx.x * 128, n0 = blockIdx.y * 128;
  int kbeg = blockIdx.z * K;
  int wave = tid >> 6, lane = tid & 63;
  int quad = lane >> 4, l16 = lane & 15;
  int wr = wave >> 1, wc = wave & 1;

  f32x4 acc[4][4];
#pragma unroll
  for (int i = 0; i < 4; i++)
#pragma unroll
    for (int j = 0; j < 4; j++) acc[i][j] = (f32x4){0.f, 0.f, 0.f, 0.f};

  for (int k0 = kbeg; k0 < kbeg + K; k0 += 64) {
#pragma unroll
    for (int t = 0; t < 4; t++) {
      int chunk = wave * 4 + t;            // 0..15, wave-uniform
      int row = chunk * 8 + (lane >> 3);   // 8 rows per chunk
      int c8 = (lane & 7) * 8;             // bf16 offset within row (16B/lane)
      const bf16* asrc;
      if constexpr (AMODE == 0) {
        asrc = A + (size_t)(m0 + row) * K + k0 + c8;
      } else {
        int m = m0 + row;
        int b = m >> 8, tt = m & 255;
        int oh = tt >> 4, ow = tt & 15;
        int p = k0 >> 8;            // patch position (BK=64 never straddles p)
        int kh = p >> 2, kw = p & 3;
        int tok = (oh * 4 + kh) * 64 + ow * 4 + kw;
        asrc = A + ((size_t)(b * 4096 + tok) << 8) + (k0 & 255) + c8;
      }
      gload_lds16(asrc, As + chunk * 512);
      gload_lds16(Bt + (size_t)(n0 + row) * ((AMODE == 1) ? 4096 : K) + k0 + c8,
                  Bs + chunk * 512);
    }
    __syncthreads();
#pragma unroll
    for (int kk = 0; kk < 64; kk += 32) {
      bf16x8 af[4], bfr[4];
#pragma unroll
      for (int mt = 0; mt < 4; mt++)
        af[mt] = *(const bf16x8*)&As[(wr * 64 + mt * 16 + l16) * 64 + kk + quad * 8];
#pragma unroll
      for (int nt = 0; nt < 4; nt++)
        bfr[nt] = *(const bf16x8*)&Bs[(wc * 64 + nt * 16 + l16) * 64 + kk + quad * 8];
#pragma unroll
      for (int mt = 0; mt < 4; mt++)
#pragma unroll
        for (int nt = 0; nt < 4; nt++)
          acc[mt][nt] = MFMA16(af[mt], bfr[nt], acc[mt][nt]);
    }
    __syncthreads();
  }

#pragma unroll
  for (int mt = 0; mt < 4; mt++) {
    int rbase = m0 + wr * 64 + mt * 16 + quad * 4;
#pragma unroll
    for (int nt = 0; nt < 4; nt++) {
      int col = n0 + wc * 64 + nt * 16 + l16;
#pragma unroll
      for (int r = 0; r < 4; r++) {
        float v = acc[mt][nt][r];
        int row = rbase + r;
        if constexpr (EMODE == 3) {
          ((float*)Cout)[(size_t)row * N + col] = v + bias[col];
        } else {  // EMODE 4
          ((float*)Cout)[((size_t)blockIdx.z * M + row) * N + col] = v;
        }
      }
    }
  }
}

// ---------------- final GEMM: BM=64, BN=256 (single n-tile -> A read once) ----------------
__global__ __launch_bounds__(256, 3) void k_gemm_out(
    const bf16* __restrict__ A, const bf16* __restrict__ Bt,
    float* __restrict__ out, const float* __restrict__ bias) {
  __shared__ alignas(16) bf16 As[64 * 64];    //  8 KB
  __shared__ alignas(16) bf16 Bs[256 * 64];   // 32 KB
  int tid = threadIdx.x;
  int m0 = blockIdx.x * 64;
  int wave = tid >> 6, lane = tid & 63;
  int quad = lane >> 4, l16 = lane & 15;

  f32x4 acc[4][4];
#pragma unroll
  for (int i = 0; i < 4; i++)
#pragma unroll
    for (int j = 0; j < 4; j++) acc[i][j] = (f32x4){0.f, 0.f, 0.f, 0.f};

  for (int k0 = 0; k0 < 256; k0 += 64) {
    int c8 = (lane & 7) * 8;
#pragma unroll
    for (int t = 0; t < 2; t++) {  // A: 8 chunks of 8 rows
      int chunk = wave * 2 + t;
      int row = chunk * 8 + (lane >> 3);
      gload_lds16(A + (size_t)(m0 + row) * 256 + k0 + c8, As + chunk * 512);
    }
#pragma unroll
    for (int t = 0; t < 8; t++) {  // B: 32 chunks (all 256 out-cols)
      int chunk = wave * 8 + t;
      int row = chunk * 8 + (lane >> 3);
      gload_lds16(Bt + (size_t)row * 256 + k0 + c8, Bs + chunk * 512);
    }
    __syncthreads();
#pragma unroll
    for (int kk = 0; kk < 64; kk += 32) {
      bf16x8 af[4], bfr[4];
#pragma unroll
      for (int mt = 0; mt < 4; mt++)
        af[mt] = *(const bf16x8*)&As[(mt * 16 + l16) * 64 + kk + quad * 8];
#pragma unroll
      for (int nt = 0; nt < 4; nt++)
        bfr[nt] = *(const bf16x8*)&Bs[(wave * 64 + nt * 16 + l16) * 64 + kk + quad * 8];
#pragma unroll
      for (int mt = 0; mt < 4; mt++)
#pragma unroll
        for (int nt = 0; nt < 4; nt++)
          acc[mt][nt] = MFMA16(af[mt], bfr[nt], acc[mt][nt]);
    }
    __syncthreads();
  }

#pragma unroll
  for (int mt = 0; mt < 4; mt++) {
    int rbase = m0 + mt * 16 + quad * 4;
#pragma unroll
    for (int nt = 0; nt < 4; nt++) {
      int col = wave * 64 + nt * 16 + l16;
      float bb = bias[col];
#pragma unroll
      for (int r = 0; r < 4; r++)
        out[(size_t)(rbase + r) * 256 + col] = acc[mt][nt][r] + bb;
    }
  }
}

// ---------------- LayerNorm (sum of 8 fp32 partials + sr_b -> bf16) ----------------
__global__ void k_ln(const float* __restrict__ part, const float* __restrict__ srb,
                     const float* __restrict__ g, const float* __restrict__ bb,
                     bf16* __restrict__ out) {
  int row = blockIdx.x * 4 + (threadIdx.x >> 6);
  int lane = threadIdx.x & 63;
  size_t off = (size_t)row * 256 + lane * 4;
  float4 v = *(const float4*)&part[off];
#pragma unroll
  for (int z = 1; z < 8; z++) {
    float4 p = *(const float4*)&part[(size_t)z * 2048 * 256 + off];
    v.x += p.x; v.y += p.y; v.z += p.z; v.w += p.w;
  }
  int c = lane * 4;
  v.x += srb[c + 0]; v.y += srb[c + 1]; v.z += srb[c + 2]; v.w += srb[c + 3];
  float s = v.x + v.y + v.z + v.w;
#pragma unroll
  for (int i = 1; i < 64; i <<= 1) s += __shfl_xor(s, i, 64);
  float mu = s * (1.f / 256.f);
  float d0 = v.x - mu, d1 = v.y - mu, d2 = v.z - mu, d3 = v.w - mu;
  float q = d0 * d0 + d1 * d1 + d2 * d2 + d3 * d3;
#pragma unroll
  for (int i = 1; i < 64; i <<= 1) q += __shfl_xor(q, i, 64);
  float rs = rsqrtf(q * (1.f / 256.f) + 1e-5f);
  bf16x4 o;
  o[0] = (bf16)(d0 * rs * g[c + 0] + bb[c + 0]);
  o[1] = (bf16)(d1 * rs * g[c + 1] + bb[c + 1]);
  o[2] = (bf16)(d2 * rs * g[c + 2] + bb[c + 2]);
  o[3] = (bf16)(d3 * rs * g[c + 3] + bb[c + 3]);
  *(bf16x4*)&out[(size_t)row * 256 + c] = o;
}

// ---------------- attention, fused Q-proj, 40KB LDS -> 4 blocks/CU ----------------
// grid (32 bh, 64 qt), block 256 (4 waves).
// R0 32KB: Wq -> K -> P.  Vq 8KB: Qs[64][64] -> V eighth dbuf 2x[64][32].
// V eighths are 32 keys wide -> global V swizzle is (d&3)<<3 (bits 3-4 stay
// inside the eighth); LDS reads apply the same XOR (both-sides, G21).
__global__ __launch_bounds__(256, 4) void k_attn(
    const bf16* __restrict__ xbf,  // [B*4096][256]
    const bf16* __restrict__ WqT,  // [256 out][256 in ^ ((out&7)<<3)]
    const bf16* __restrict__ Kg,   // [32][256][64]  cols ^ ((key&7)<<3)
    const bf16* __restrict__ Vg,   // [32][64][256]  cols ^ ((d&3)<<3)
    bf16* __restrict__ O) {        // [B*4096][256]
  int bh = blockIdx.x, qt = blockIdx.y;
  int b = bh >> 2, h = bh & 3;
  int tid = threadIdx.x, wave = tid >> 6, lane = tid & 63;
  int quad = lane >> 4, l16 = lane & 15;

  __shared__ alignas(16) bf16 smem[20480];  // 40960 B
  bf16* R0 = smem;          // [64][256] Wq -> [256][64] K -> [64][256] P
  bf16* Vq = smem + 16384;  // 8KB: Qs -> V eighth double-buffer

  const bf16* Kbh = Kg + ((size_t)bh << 14);
  const bf16* Vbh = Vg + ((size_t)bh << 14);
  const bf16* Wqh = WqT + ((size_t)(h * 64) << 8);

  // ---- stage Wq head (32KB); x A-frags -> regs ----
#pragma unroll
  for (int t = 0; t < 8; t++) {
    int chunk = t * 4 + wave;
    gload_lds16(Wqh + chunk * 512 + lane * 8, R0 + chunk * 512);
  }
  const bf16* xrow =
      xbf + (((size_t)(b * 4096 + qt * 64 + wave * 16 + l16)) << 8) + quad * 8;
  bf16x8 ax[8];
#pragma unroll
  for (int j = 0; j < 8; j++) ax[j] = *(const bf16x8*)(xrow + j * 32);

  __syncthreads();  // B1: Wq resident (ax drained too)

  // ---- Q = x @ Wq_head^T ----
  f32x4 q[4];
#pragma unroll
  for (int i = 0; i < 4; i++) q[i] = (f32x4){0.f, 0.f, 0.f, 0.f};
  __builtin_amdgcn_s_setprio(1);
#pragma unroll
  for (int j = 0; j < 8; j++) {
#pragma unroll
    for (int nt = 0; nt < 4; nt++) {
      int wrow = nt * 16 + l16;
      bf16x8 bw = *(const bf16x8*)&R0[wrow * 256 +
                                      ((j * 32 + quad * 8) ^ ((wrow & 7) << 3))];
      q[nt] = MFMA16(ax[j], bw, q[nt]);
    }
  }
  __builtin_amdgcn_s_setprio(0);

  // ---- Qs -> Vq (swizzled [64][64]); read aq; then one barrier covers
  //      Wq-read completion AND Qs-read completion for all waves ----
#pragma unroll
  for (int nt = 0; nt < 4; nt++)
#pragma unroll
    for (int r = 0; r < 4; r++) {
      int qr = wave * 16 + quad * 4 + r;
      Vq[qr * 64 + ((nt * 16 + l16) ^ ((qr & 7) << 3))] = (bf16)q[nt][r];
    }
  int arow = wave * 16 + l16;
  int asw = (arow & 7) << 3;
  bf16x8 aq0 = *(const bf16x8*)&Vq[arow * 64 + ((quad * 8) ^ asw)];
  bf16x8 aq1 = *(const bf16x8*)&Vq[arow * 64 + ((32 + quad * 8) ^ asw)];
  __syncthreads();  // B2': R0 free (Wq dead) and Vq free (Qs dead) everywhere

  // ---- stage K (32KB) -> R0; V eighths 0,1 -> Vq (1KB chunk per wave each) ----
#pragma unroll
  for (int t = 0; t < 8; t++) {
    int chunk = t * 4 + wave;
    gload_lds16(Kbh + chunk * 512 + lane * 8, R0 + chunk * 512);
  }
#pragma unroll
  for (int e = 0; e < 2; e++) {
    gload_lds16(Vbh + (wave * 16 + (lane >> 2)) * 256 + e * 32 + (lane & 3) * 8,
                Vq + e * 2048 + wave * 512);
  }
  __syncthreads();  // B3: K + eighths 0,1 resident

  // ---- S = Q K^T ----
  f32x4 s[16];
#pragma unroll
  for (int i = 0; i < 16; i++) s[i] = (f32x4){0.f, 0.f, 0.f, 0.f};
  __builtin_amdgcn_s_setprio(1);
#pragma unroll
  for (int nt = 0; nt < 16; nt++) {
    int krow = nt * 16 + l16;
    const bf16* kb = R0 + krow * 64;
    int sw = (krow & 7) << 3;
    bf16x8 b0 = *(const bf16x8*)(kb + ((quad * 8) ^ sw));
    bf16x8 b1 = *(const bf16x8*)(kb + ((32 + quad * 8) ^ sw));
    s[nt] = MFMA16(aq0, b0, s[nt]);
    s[nt] = MFMA16(aq1, b1, s[nt]);
  }
  __builtin_amdgcn_s_setprio(0);

  // softmax over 256 keys
  const float scale = 0.125f;
#pragma unroll
  for (int r = 0; r < 4; r++) {
    float m = -1e30f;
#pragma unroll
    for (int nt = 0; nt < 16; nt++) m = fmaxf(m, s[nt][r]);
#pragma unroll
    for (int i = 1; i < 16; i <<= 1) m = fmaxf(m, __shfl_xor(m, i, 64));
    float sum = 0.f;
#pragma unroll
    for (int nt = 0; nt < 16; nt++) {
      float e = __expf((s[nt][r] - m) * scale);
      s[nt][r] = e;
      sum += e;
    }
#pragma unroll
    for (int i = 1; i < 16; i <<= 1) sum += __shfl_xor(sum, i, 64);
    float inv = 1.f / sum;
#pragma unroll
    for (int nt = 0; nt < 16; nt++) s[nt][r] *= inv;
  }

  __syncthreads();  // B4: K reads done -> R0 free for P

  // ---- P -> R0 swizzled [64][256] (wave-private rows) ----
#pragma unroll
  for (int nt = 0; nt < 16; nt++)
#pragma unroll
    for (int r = 0; r < 4; r++) {
      int prow = wave * 16 + quad * 4 + r;
      R0[prow * 256 + ((nt * 16 + l16) ^ ((prow & 7) << 3))] = (bf16)s[nt][r];
    }

  const bf16* pb = R0 + arow * 256;
  f32x4 o[4];
#pragma unroll
  for (int i = 0; i < 4; i++) o[i] = (f32x4){0.f, 0.f, 0.f, 0.f};

  // ---- O = P V over 8 key-eighths, double-buffered in Vq ----
#pragma unroll
  for (int e = 0; e < 8; e++) {
    const bf16* Vbuf = Vq + (e & 1) * 2048;
    __builtin_amdgcn_s_setprio(1);
    bf16x8 ap = *(const bf16x8*)(pb + ((e * 32 + quad * 8) ^ asw));
#pragma unroll
    for (int nt = 0; nt < 4; nt++) {
      int vrow = nt * 16 + l16;
      bf16x8 bv = *(const bf16x8*)&Vbuf[vrow * 32 +
                                        ((quad * 8) ^ ((vrow & 3) << 3))];
      o[nt] = MFMA16(ap, bv, o[nt]);
    }
    __builtin_amdgcn_s_setprio(0);
    if (e < 7) {
      __syncthreads();  // buf (e&1) reads done everywhere; eighth e+1 resident
      if (e < 6) {      // stage eighth e+2 into the buffer just freed
        gload_lds16(
            Vbh + (wave * 16 + (lane >> 2)) * 256 + (e + 2) * 32 + (lane & 3) * 8,
            Vq + (e & 1) * 2048 + wave * 512);
      }
    }
  }

  size_t orow = (size_t)b * 4096 + qt * 64 + wave * 16 + quad * 4;
#pragma unroll
  for (int nt = 0; nt < 4; nt++) {
    int col = h * 64 + nt * 16 + l16;
#pragma unroll
    for (int r = 0; r < 4; r++) O[(orow + r) * 256 + col] = (bf16)o[nt][r];
  }
}

// ---------------- launch ----------------
extern "C" void kernel_launch(void* const* d_in, const int* in_sizes, int n_in,
                              void* d_out, int out_size, void* d_ws, size_t ws_size,
                              hipStream_t stream) {
  (void)in_sizes; (void)n_in; (void)out_size; (void)ws_size;
  const float* x   = (const float*)d_in[0];
  const float* Wq  = (const float*)d_in[3];
  const float* Wkv = (const float*)d_in[4];
  const float* srw = (const float*)d_in[5];
  const float* srb = (const float*)d_in[6];
  const float* lng = (const float*)d_in[7];
  const float* lnb = (const float*)d_in[8];
  const float* Wo  = (const float*)d_in[9];
  const float* bo  = (const float*)d_in[10];
  float* out = (float*)d_out;

  char* ws = (char*)d_ws;
  bf16*  x_bf  = (bf16*)(ws + 0);          // 16,777,216 B
  bf16*  AObuf = (bf16*)(ws + 16777216);   // 16,777,216
  float* convp = (float*)(ws + 33554432);  // 16,777,216 (8 partials)
  bf16*  WqT   = (bf16*)(ws + 50331648);   //    131,072
  bf16*  WkvT  = (bf16*)(ws + 50462720);   //    262,144
  bf16*  WoT   = (bf16*)(ws + 50724864);   //    131,072
  bf16*  srwT  = (bf16*)(ws + 50855936);   //  2,097,152
  bf16*  xln   = (bf16*)(ws + 52953088);   //  1,048,576
  bf16*  kvbuf = (bf16*)(ws + 54001664);   //  2,097,152 (K then V^T, swizzled)

  k_prep<<<6144, 256, 0, stream>>>(x, Wq, Wkv, Wo, srw, x_bf, WqT, WkvT, WoT, srwT);
  // conv (im2col GEMM), split-K 8x512 -> fp32 partials [8][2048][256]
  k_gemm128<1, 4><<<dim3(16, 2, 8), 256, 0, stream>>>(x_bf, srwT, convp, nullptr, 2048, 256, 512);
  // LayerNorm (+partial reduce +sr_b) -> bf16 [2048][256]
  k_ln<<<512, 256, 0, stream>>>(convp, srb, lng, lnb, xln);
  // KV = xln @ Wkv -> K, V^T (swizzled) bf16
  k_gemm<0, 2><<<dim3(32, 8), 256, 0, stream>>>(xln, WkvT, kvbuf, nullptr, 2048, 512, 256);
  // attention (Q-projection fused; 40KB LDS -> 4 blocks/CU)
  k_attn<<<dim3(32, 64), 256, 0, stream>>>(x_bf, WqT, kvbuf, kvbuf + (size_t)32 * 256 * 64, AObuf);
  // out = AO @ Wo + bo -> fp32 d_out (BM=64, BN=256: AO read once)
  k_gemm_out<<<512, 256, 0, stream>>>(AObuf, WoT, out, bo);
}

// Round 14
// 171.871 us; speedup vs baseline: 1.0590x; 1.0046x over previous
//
#include <hip/hip_runtime.h>

typedef __bf16 bf16;
typedef bf16 bf16x8 __attribute__((ext_vector_type(8)));
typedef bf16 bf16x4 __attribute__((ext_vector_type(4)));
typedef float f32x4 __attribute__((ext_vector_type(4)));

#define MFMA16(a, b, c) __builtin_amdgcn_mfma_f32_16x16x32_bf16(a, b, c, 0, 0, 0)

// async global->LDS, 16B per lane; lds dest is wave-uniform base (+lane*16 by HW)
__device__ __forceinline__ void gload_lds16(const bf16* g, bf16* l) {
  __builtin_amdgcn_global_load_lds(
      (const __attribute__((address_space(1))) void*)g,
      (__attribute__((address_space(3))) void*)l, 16, 0, 0);
}

// ---------------- merged prep kernel ----------------
// blocks [0,4096):      x fp32 -> bf16 (8 el/thread, 16B loads+stores)
// blocks [4096,5120):   W transposes (Wq swizzled | Wkv | Wo plain)
// blocks [5120,6144):   sr_w [o][i][p] -> srwT [o][p*256+i]
__global__ void k_prep(const float* __restrict__ x, const float* __restrict__ Wq,
                       const float* __restrict__ Wkv, const float* __restrict__ Wo,
                       const float* __restrict__ srw,
                       bf16* __restrict__ x_bf, bf16* __restrict__ WqT,
                       bf16* __restrict__ WkvT, bf16* __restrict__ WoT,
                       bf16* __restrict__ srwT) {
  int bid = blockIdx.x, tid = threadIdx.x;
  if (bid < 4096) {
    int i = (bid * 256 + tid) * 8;
    float4 v0 = *(const float4*)(x + i);
    float4 v1 = *(const float4*)(x + i + 4);
    bf16x8 o;
    o[0] = (bf16)v0.x; o[1] = (bf16)v0.y; o[2] = (bf16)v0.z; o[3] = (bf16)v0.w;
    o[4] = (bf16)v1.x; o[5] = (bf16)v1.y; o[6] = (bf16)v1.z; o[7] = (bf16)v1.w;
    *(bf16x8*)(x_bf + i) = o;
  } else if (bid < 5120) {
    int id = (bid - 4096) * 256 + tid;  // 0..262143
    if (id < 65536) {                   // WqT (swizzled)
      int c = id >> 8, r = id & 255;    // c = out, r = in
      WqT[c * 256 + (r ^ ((c & 7) << 3))] = (bf16)Wq[r * 256 + c];
    } else if (id < 196608) {           // WkvT
      int l = id - 65536;
      int c = l >> 8, r = l & 255;      // c in 0..511
      WkvT[l] = (bf16)Wkv[r * 512 + c];
    } else {                            // WoT (plain transpose [out][in])
      int l = id - 196608;
      int c = l >> 8, r = l & 255;
      WoT[l] = (bf16)Wo[r * 256 + c];
    }
  } else {
    int id4 = ((bid - 5120) * 256 + tid) * 4;  // input-linear o*4096+i*16+p
    int o = id4 >> 12, rem = id4 & 4095;
    int i = rem >> 4, p = rem & 15;            // p in {0,4,8,12}
    float4 v = *(const float4*)(srw + id4);
    srwT[(o << 12) + ((p + 0) << 8) + i] = (bf16)v.x;
    srwT[(o << 12) + ((p + 1) << 8) + i] = (bf16)v.y;
    srwT[(o << 12) + ((p + 2) << 8) + i] = (bf16)v.z;
    srwT[(o << 12) + ((p + 3) << 8) + i] = (bf16)v.w;
  }
}

// ---------------- 64x64-tile MFMA GEMM (KV projection) ----------------
// EMODE 2: KV scatter (XOR-swizzled cols for attn's global_load_lds staging):
//          K  -> [bh][key][d ^ ((key&7)<<3)]         (64-wide rows, 8-group XOR)
//          V^T-> [bh][d][key ^ ((d&3)<<3)]           (32-wide eighths: bits 3-4 only)
template <int AMODE, int EMODE>
__global__ __launch_bounds__(256, 2) void k_gemm(
    const bf16* __restrict__ A, const bf16* __restrict__ Bt,
    void* __restrict__ Cout, const float* __restrict__ bias,
    int M, int N, int K) {
  constexpr int LDT = 72;  // 64 + 8 pad
  __shared__ alignas(16) bf16 As[64 * LDT];
  __shared__ alignas(16) bf16 Bs[64 * LDT];
  int tid = threadIdx.x;
  int m0 = blockIdx.x * 64, n0 = blockIdx.y * 64;
  int kbeg = blockIdx.z * K;
  int wave = tid >> 6, lane = tid & 63;
  int quad = lane >> 4, l16 = lane & 15;

  f32x4 acc[4];
#pragma unroll
  for (int i = 0; i < 4; i++) acc[i] = (f32x4){0.f, 0.f, 0.f, 0.f};

  for (int k0 = kbeg; k0 < kbeg + K; k0 += 64) {
#pragma unroll
    for (int t = 0; t < 2; t++) {
      int c = tid + t * 256;
      int row = c >> 3, c8 = (c & 7) * 8;
      *(bf16x8*)&As[row * LDT + c8] =
          *(const bf16x8*)(A + (size_t)(m0 + row) * K + k0 + c8);
      *(bf16x8*)&Bs[row * LDT + c8] =
          *(const bf16x8*)(Bt + (size_t)(n0 + row) * K + k0 + c8);
    }
    __syncthreads();
#pragma unroll
    for (int kk = 0; kk < 64; kk += 32) {
      bf16x8 af = *(const bf16x8*)&As[(wave * 16 + l16) * LDT + kk + quad * 8];
#pragma unroll
      for (int nt = 0; nt < 4; nt++) {
        bf16x8 bfr = *(const bf16x8*)&Bs[(nt * 16 + l16) * LDT + kk + quad * 8];
        acc[nt] = MFMA16(af, bfr, acc[nt]);
      }
    }
    __syncthreads();
  }

  int rbase = m0 + wave * 16 + quad * 4;
#pragma unroll
  for (int nt = 0; nt < 4; nt++) {
    int col = n0 + nt * 16 + l16;
#pragma unroll
    for (int r = 0; r < 4; r++) {
      float v = acc[nt][r];
      int row = rbase + r;
      if constexpr (EMODE == 2) {
        int b = row >> 8, key = row & 255;
        int isv = col >> 8, c2 = col & 255;
        int hh = c2 >> 6, d = c2 & 63;
        int bh = b * 4 + hh;
        bf16* dst = (bf16*)Cout;
        if (isv == 0)
          dst[(((size_t)bh) * 256 + key) * 64 + (d ^ ((key & 7) << 3))] = (bf16)v;
        else
          dst[32 * 256 * 64 + (((size_t)bh) * 64 + d) * 256 + (key ^ ((d & 3) << 3))] = (bf16)v;
      } else {
        ((float*)Cout)[(size_t)row * N + col] = v + bias[col];
      }
    }
  }
}

// ---------------- 128x128-tile MFMA GEMM (m97 structure; conv im2col) ----------------
template <int AMODE, int EMODE>
__global__ __launch_bounds__(256, 2) void k_gemm128(
    const bf16* __restrict__ A, const bf16* __restrict__ Bt,
    void* __restrict__ Cout, const float* __restrict__ bias,
    int M, int N, int K) {
  __shared__ alignas(16) bf16 As[128 * 64];
  __shared__ alignas(16) bf16 Bs[128 * 64];
  int tid = threadIdx.x;
  int m0 = blockIdx.x * 128, n0 = blockIdx.y * 128;
  int kbeg = blockIdx.z * K;
  int wave = tid >> 6, lane = tid & 63;
  int quad = lane >> 4, l16 = lane & 15;
  int wr = wave >> 1, wc = wave & 1;

  f32x4 acc[4][4];
#pragma unroll
  for (int i = 0; i < 4; i++)
#pragma unroll
    for (int j = 0; j < 4; j++) acc[i][j] = (f32x4){0.f, 0.f, 0.f, 0.f};

  for (int k0 = kbeg; k0 < kbeg + K; k0 += 64) {
#pragma unroll
    for (int t = 0; t < 4; t++) {
      int chunk = wave * 4 + t;            // 0..15, wave-uniform
      int row = chunk * 8 + (lane >> 3);   // 8 rows per chunk
      int c8 = (lane & 7) * 8;             // bf16 offset within row (16B/lane)
      const bf16* asrc;
      if constexpr (AMODE == 0) {
        asrc = A + (size_t)(m0 + row) * K + k0 + c8;
      } else {
        int m = m0 + row;
        int b = m >> 8, tt = m & 255;
        int oh = tt >> 4, ow = tt & 15;
        int p = k0 >> 8;            // patch position (BK=64 never straddles p)
        int kh = p >> 2, kw = p & 3;
        int tok = (oh * 4 + kh) * 64 + ow * 4 + kw;
        asrc = A + ((size_t)(b * 4096 + tok) << 8) + (k0 & 255) + c8;
      }
      gload_lds16(asrc, As + chunk * 512);
      gload_lds16(Bt + (size_t)(n0 + row) * ((AMODE == 1) ? 4096 : K) + k0 + c8,
                  Bs + chunk * 512);
    }
    __syncthreads();
#pragma unroll
    for (int kk = 0; kk < 64; kk += 32) {
      bf16x8 af[4], bfr[4];
#pragma unroll
      for (int mt = 0; mt < 4; mt++)
        af[mt] = *(const bf16x8*)&As[(wr * 64 + mt * 16 + l16) * 64 + kk + quad * 8];
#pragma unroll
      for (int nt = 0; nt < 4; nt++)
        bfr[nt] = *(const bf16x8*)&Bs[(wc * 64 + nt * 16 + l16) * 64 + kk + quad * 8];
#pragma unroll
      for (int mt = 0; mt < 4; mt++)
#pragma unroll
        for (int nt = 0; nt < 4; nt++)
          acc[mt][nt] = MFMA16(af[mt], bfr[nt], acc[mt][nt]);
    }
    __syncthreads();
  }

#pragma unroll
  for (int mt = 0; mt < 4; mt++) {
    int rbase = m0 + wr * 64 + mt * 16 + quad * 4;
#pragma unroll
    for (int nt = 0; nt < 4; nt++) {
      int col = n0 + wc * 64 + nt * 16 + l16;
#pragma unroll
      for (int r = 0; r < 4; r++) {
        float v = acc[mt][nt][r];
        int row = rbase + r;
        if constexpr (EMODE == 3) {
          ((float*)Cout)[(size_t)row * N + col] = v + bias[col];
        } else {  // EMODE 4
          ((float*)Cout)[((size_t)blockIdx.z * M + row) * N + col] = v;
        }
      }
    }
  }
}

// ---------------- final GEMM: BM=64, BN=256 (single n-tile -> A read once) ----------------
__global__ __launch_bounds__(256, 3) void k_gemm_out(
    const bf16* __restrict__ A, const bf16* __restrict__ Bt,
    float* __restrict__ out, const float* __restrict__ bias) {
  __shared__ alignas(16) bf16 As[64 * 64];    //  8 KB
  __shared__ alignas(16) bf16 Bs[256 * 64];   // 32 KB
  int tid = threadIdx.x;
  int m0 = blockIdx.x * 64;
  int wave = tid >> 6, lane = tid & 63;
  int quad = lane >> 4, l16 = lane & 15;

  f32x4 acc[4][4];
#pragma unroll
  for (int i = 0; i < 4; i++)
#pragma unroll
    for (int j = 0; j < 4; j++) acc[i][j] = (f32x4){0.f, 0.f, 0.f, 0.f};

  for (int k0 = 0; k0 < 256; k0 += 64) {
    int c8 = (lane & 7) * 8;
#pragma unroll
    for (int t = 0; t < 2; t++) {  // A: 8 chunks of 8 rows
      int chunk = wave * 2 + t;
      int row = chunk * 8 + (lane >> 3);
      gload_lds16(A + (size_t)(m0 + row) * 256 + k0 + c8, As + chunk * 512);
    }
#pragma unroll
    for (int t = 0; t < 8; t++) {  // B: 32 chunks (all 256 out-cols)
      int chunk = wave * 8 + t;
      int row = chunk * 8 + (lane >> 3);
      gload_lds16(Bt + (size_t)row * 256 + k0 + c8, Bs + chunk * 512);
    }
    __syncthreads();
#pragma unroll
    for (int kk = 0; kk < 64; kk += 32) {
      bf16x8 af[4], bfr[4];
#pragma unroll
      for (int mt = 0; mt < 4; mt++)
        af[mt] = *(const bf16x8*)&As[(mt * 16 + l16) * 64 + kk + quad * 8];
#pragma unroll
      for (int nt = 0; nt < 4; nt++)
        bfr[nt] = *(const bf16x8*)&Bs[(wave * 64 + nt * 16 + l16) * 64 + kk + quad * 8];
#pragma unroll
      for (int mt = 0; mt < 4; mt++)
#pragma unroll
        for (int nt = 0; nt < 4; nt++)
          acc[mt][nt] = MFMA16(af[mt], bfr[nt], acc[mt][nt]);
    }
    __syncthreads();
  }

#pragma unroll
  for (int mt = 0; mt < 4; mt++) {
    int rbase = m0 + mt * 16 + quad * 4;
#pragma unroll
    for (int nt = 0; nt < 4; nt++) {
      int col = wave * 64 + nt * 16 + l16;
      float bb = bias[col];
#pragma unroll
      for (int r = 0; r < 4; r++)
        out[(size_t)(rbase + r) * 256 + col] = acc[mt][nt][r] + bb;
    }
  }
}

// ---------------- LayerNorm (sum of 16 fp32 partials + sr_b -> bf16) ----------------
__global__ void k_ln(const float* __restrict__ part, const float* __restrict__ srb,
                     const float* __restrict__ g, const float* __restrict__ bb,
                     bf16* __restrict__ out) {
  int row = blockIdx.x * 4 + (threadIdx.x >> 6);
  int lane = threadIdx.x & 63;
  size_t off = (size_t)row * 256 + lane * 4;
  float4 v = *(const float4*)&part[off];
#pragma unroll
  for (int z = 1; z < 16; z++) {
    float4 p = *(const float4*)&part[(size_t)z * 2048 * 256 + off];
    v.x += p.x; v.y += p.y; v.z += p.z; v.w += p.w;
  }
  int c = lane * 4;
  v.x += srb[c + 0]; v.y += srb[c + 1]; v.z += srb[c + 2]; v.w += srb[c + 3];
  float s = v.x + v.y + v.z + v.w;
#pragma unroll
  for (int i = 1; i < 64; i <<= 1) s += __shfl_xor(s, i, 64);
  float mu = s * (1.f / 256.f);
  float d0 = v.x - mu, d1 = v.y - mu, d2 = v.z - mu, d3 = v.w - mu;
  float q = d0 * d0 + d1 * d1 + d2 * d2 + d3 * d3;
#pragma unroll
  for (int i = 1; i < 64; i <<= 1) q += __shfl_xor(q, i, 64);
  float rs = rsqrtf(q * (1.f / 256.f) + 1e-5f);
  bf16x4 o;
  o[0] = (bf16)(d0 * rs * g[c + 0] + bb[c + 0]);
  o[1] = (bf16)(d1 * rs * g[c + 1] + bb[c + 1]);
  o[2] = (bf16)(d2 * rs * g[c + 2] + bb[c + 2]);
  o[3] = (bf16)(d3 * rs * g[c + 3] + bb[c + 3]);
  *(bf16x4*)&out[(size_t)row * 256 + c] = o;
}

// ---------------- attention, fused Q-proj, 40KB LDS -> 4 blocks/CU (R12 winner) ----
// grid (32 bh, 64 qt), block 256 (4 waves).
// R0 32KB: Wq -> K -> P.  Vq 8KB: Qs[64][64] -> V eighth dbuf 2x[64][32].
__global__ __launch_bounds__(256, 4) void k_attn(
    const bf16* __restrict__ xbf,  // [B*4096][256]
    const bf16* __restrict__ WqT,  // [256 out][256 in ^ ((out&7)<<3)]
    const bf16* __restrict__ Kg,   // [32][256][64]  cols ^ ((key&7)<<3)
    const bf16* __restrict__ Vg,   // [32][64][256]  cols ^ ((d&3)<<3)
    bf16* __restrict__ O) {        // [B*4096][256]
  int bh = blockIdx.x, qt = blockIdx.y;
  int b = bh >> 2, h = bh & 3;
  int tid = threadIdx.x, wave = tid >> 6, lane = tid & 63;
  int quad = lane >> 4, l16 = lane & 15;

  __shared__ alignas(16) bf16 smem[20480];  // 40960 B
  bf16* R0 = smem;          // [64][256] Wq -> [256][64] K -> [64][256] P
  bf16* Vq = smem + 16384;  // 8KB: Qs -> V eighth double-buffer

  const bf16* Kbh = Kg + ((size_t)bh << 14);
  const bf16* Vbh = Vg + ((size_t)bh << 14);
  const bf16* Wqh = WqT + ((size_t)(h * 64) << 8);

  // ---- stage Wq head (32KB); x A-frags -> regs ----
#pragma unroll
  for (int t = 0; t < 8; t++) {
    int chunk = t * 4 + wave;
    gload_lds16(Wqh + chunk * 512 + lane * 8, R0 + chunk * 512);
  }
  const bf16* xrow =
      xbf + (((size_t)(b * 4096 + qt * 64 + wave * 16 + l16)) << 8) + quad * 8;
  bf16x8 ax[8];
#pragma unroll
  for (int j = 0; j < 8; j++) ax[j] = *(const bf16x8*)(xrow + j * 32);

  __syncthreads();  // B1: Wq resident (ax drained too)

  // ---- Q = x @ Wq_head^T ----
  f32x4 q[4];
#pragma unroll
  for (int i = 0; i < 4; i++) q[i] = (f32x4){0.f, 0.f, 0.f, 0.f};
  __builtin_amdgcn_s_setprio(1);
#pragma unroll
  for (int j = 0; j < 8; j++) {
#pragma unroll
    for (int nt = 0; nt < 4; nt++) {
      int wrow = nt * 16 + l16;
      bf16x8 bw = *(const bf16x8*)&R0[wrow * 256 +
                                      ((j * 32 + quad * 8) ^ ((wrow & 7) << 3))];
      q[nt] = MFMA16(ax[j], bw, q[nt]);
    }
  }
  __builtin_amdgcn_s_setprio(0);

  // ---- Qs -> Vq (swizzled [64][64]); read aq; then one barrier covers
  //      Wq-read completion AND Qs-read completion for all waves ----
#pragma unroll
  for (int nt = 0; nt < 4; nt++)
#pragma unroll
    for (int r = 0; r < 4; r++) {
      int qr = wave * 16 + quad * 4 + r;
      Vq[qr * 64 + ((nt * 16 + l16) ^ ((qr & 7) << 3))] = (bf16)q[nt][r];
    }
  int arow = wave * 16 + l16;
  int asw = (arow & 7) << 3;
  bf16x8 aq0 = *(const bf16x8*)&Vq[arow * 64 + ((quad * 8) ^ asw)];
  bf16x8 aq1 = *(const bf16x8*)&Vq[arow * 64 + ((32 + quad * 8) ^ asw)];
  __syncthreads();  // B2': R0 free (Wq dead) and Vq free (Qs dead) everywhere

  // ---- stage K (32KB) -> R0; V eighths 0,1 -> Vq (1KB chunk per wave each) ----
#pragma unroll
  for (int t = 0; t < 8; t++) {
    int chunk = t * 4 + wave;
    gload_lds16(Kbh + chunk * 512 + lane * 8, R0 + chunk * 512);
  }
#pragma unroll
  for (int e = 0; e < 2; e++) {
    gload_lds16(Vbh + (wave * 16 + (lane >> 2)) * 256 + e * 32 + (lane & 3) * 8,
                Vq + e * 2048 + wave * 512);
  }
  __syncthreads();  // B3: K + eighths 0,1 resident

  // ---- S = Q K^T ----
  f32x4 s[16];
#pragma unroll
  for (int i = 0; i < 16; i++) s[i] = (f32x4){0.f, 0.f, 0.f, 0.f};
  __builtin_amdgcn_s_setprio(1);
#pragma unroll
  for (int nt = 0; nt < 16; nt++) {
    int krow = nt * 16 + l16;
    const bf16* kb = R0 + krow * 64;
    int sw = (krow & 7) << 3;
    bf16x8 b0 = *(const bf16x8*)(kb + ((quad * 8) ^ sw));
    bf16x8 b1 = *(const bf16x8*)(kb + ((32 + quad * 8) ^ sw));
    s[nt] = MFMA16(aq0, b0, s[nt]);
    s[nt] = MFMA16(aq1, b1, s[nt]);
  }
  __builtin_amdgcn_s_setprio(0);

  // softmax over 256 keys
  const float scale = 0.125f;
#pragma unroll
  for (int r = 0; r < 4; r++) {
    float m = -1e30f;
#pragma unroll
    for (int nt = 0; nt < 16; nt++) m = fmaxf(m, s[nt][r]);
#pragma unroll
    for (int i = 1; i < 16; i <<= 1) m = fmaxf(m, __shfl_xor(m, i, 64));
    float sum = 0.f;
#pragma unroll
    for (int nt = 0; nt < 16; nt++) {
      float e = __expf((s[nt][r] - m) * scale);
      s[nt][r] = e;
      sum += e;
    }
#pragma unroll
    for (int i = 1; i < 16; i <<= 1) sum += __shfl_xor(sum, i, 64);
    float inv = 1.f / sum;
#pragma unroll
    for (int nt = 0; nt < 16; nt++) s[nt][r] *= inv;
  }

  __syncthreads();  // B4: K reads done -> R0 free for P

  // ---- P -> R0 swizzled [64][256] (wave-private rows) ----
#pragma unroll
  for (int nt = 0; nt < 16; nt++)
#pragma unroll
    for (int r = 0; r < 4; r++) {
      int prow = wave * 16 + quad * 4 + r;
      R0[prow * 256 + ((nt * 16 + l16) ^ ((prow & 7) << 3))] = (bf16)s[nt][r];
    }

  const bf16* pb = R0 + arow * 256;
  f32x4 o[4];
#pragma unroll
  for (int i = 0; i < 4; i++) o[i] = (f32x4){0.f, 0.f, 0.f, 0.f};

  // ---- O = P V over 8 key-eighths, double-buffered in Vq ----
#pragma unroll
  for (int e = 0; e < 8; e++) {
    const bf16* Vbuf = Vq + (e & 1) * 2048;
    __builtin_amdgcn_s_setprio(1);
    bf16x8 ap = *(const bf16x8*)(pb + ((e * 32 + quad * 8) ^ asw));
#pragma unroll
    for (int nt = 0; nt < 4; nt++) {
      int vrow = nt * 16 + l16;
      bf16x8 bv = *(const bf16x8*)&Vbuf[vrow * 32 +
                                        ((quad * 8) ^ ((vrow & 3) << 3))];
      o[nt] = MFMA16(ap, bv, o[nt]);
    }
    __builtin_amdgcn_s_setprio(0);
    if (e < 7) {
      __syncthreads();  // buf (e&1) reads done everywhere; eighth e+1 resident
      if (e < 6) {      // stage eighth e+2 into the buffer just freed
        gload_lds16(
            Vbh + (wave * 16 + (lane >> 2)) * 256 + (e + 2) * 32 + (lane & 3) * 8,
            Vq + (e & 1) * 2048 + wave * 512);
      }
    }
  }

  size_t orow = (size_t)b * 4096 + qt * 64 + wave * 16 + quad * 4;
#pragma unroll
  for (int nt = 0; nt < 4; nt++) {
    int col = h * 64 + nt * 16 + l16;
#pragma unroll
    for (int r = 0; r < 4; r++) O[(orow + r) * 256 + col] = (bf16)o[nt][r];
  }
}

// ---------------- launch ----------------
extern "C" void kernel_launch(void* const* d_in, const int* in_sizes, int n_in,
                              void* d_out, int out_size, void* d_ws, size_t ws_size,
                              hipStream_t stream) {
  (void)in_sizes; (void)n_in; (void)out_size; (void)ws_size;
  const float* x   = (const float*)d_in[0];
  const float* Wq  = (const float*)d_in[3];
  const float* Wkv = (const float*)d_in[4];
  const float* srw = (const float*)d_in[5];
  const float* srb = (const float*)d_in[6];
  const float* lng = (const float*)d_in[7];
  const float* lnb = (const float*)d_in[8];
  const float* Wo  = (const float*)d_in[9];
  const float* bo  = (const float*)d_in[10];
  float* out = (float*)d_out;

  char* ws = (char*)d_ws;
  bf16*  x_bf  = (bf16*)(ws + 0);          // 16,777,216 B
  bf16*  AObuf = (bf16*)(ws + 16777216);   // 16,777,216
  float* convp = (float*)(ws + 33554432);  // 33,554,432 (16 partials)
  bf16*  WqT   = (bf16*)(ws + 67108864);   //    131,072
  bf16*  WkvT  = (bf16*)(ws + 67239936);   //    262,144
  bf16*  WoT   = (bf16*)(ws + 67502080);   //    131,072
  bf16*  srwT  = (bf16*)(ws + 67633152);   //  2,097,152
  bf16*  xln   = (bf16*)(ws + 69730304);   //  1,048,576
  bf16*  kvbuf = (bf16*)(ws + 70778880);   //  2,097,152 (K then V^T, swizzled)

  k_prep<<<6144, 256, 0, stream>>>(x, Wq, Wkv, Wo, srw, x_bf, WqT, WkvT, WoT, srwT);
  // conv (im2col GEMM), split-K 16x256 -> fp32 partials [16][2048][256]
  // (each 256-wide K-slice is exactly one patch position -> gather is contiguous)
  k_gemm128<1, 4><<<dim3(16, 2, 16), 256, 0, stream>>>(x_bf, srwT, convp, nullptr, 2048, 256, 256);
  // LayerNorm (+16-partial reduce +sr_b) -> bf16 [2048][256]
  k_ln<<<512, 256, 0, stream>>>(convp, srb, lng, lnb, xln);
  // KV = xln @ Wkv -> K, V^T (swizzled) bf16
  k_gemm<0, 2><<<dim3(32, 8), 256, 0, stream>>>(xln, WkvT, kvbuf, nullptr, 2048, 512, 256);
  // attention (Q-projection fused; 40KB LDS -> 4 blocks/CU)
  k_attn<<<dim3(32, 64), 256, 0, stream>>>(x_bf, WqT, kvbuf, kvbuf + (size_t)32 * 256 * 64, AObuf);
  // out = AO @ Wo + bo -> fp32 d_out (BM=64, BN=256: AO read once)
  k_gemm_out<<<512, 256, 0, stream>>>(AObuf, WoT, out, bo);
}